// Round 20
// baseline (1968.283 us; speedup 1.0000x reference)
//
#include <hip/hip_runtime.h>
#include <math.h>

// ============================================================================
// PatchTST/Autoformer hybrid forward on MI355X (gfx950).  Round 20.
//  - NEW: gemm128x256_p3 = 2-buffer ring (48 KB LDS -> 3 blk/CU), vmcnt(3),
//    for non-dmode GEMMs (QKV / Y / FFN-W1): more TLP to hide barriers.
//  - gemm128x256 (3-ring, 72 KB, dmode decomp epilogue) kept for wcomb/W2.
//  - R19 agg LDS-staging + head K-split 32 kept.  Folds #1,#2,#3 kept.
// ============================================================================

typedef unsigned short u16;
typedef short s16x8 __attribute__((ext_vector_type(8)));
typedef u16 u16x8 __attribute__((ext_vector_type(8)));
typedef float f32x4 __attribute__((ext_vector_type(4)));

#define MROWS 43008   // 672 * 64
#define NSEQ  672

__device__ __forceinline__ float bf2f(u16 b) {
  union { unsigned u; float f; } v; v.u = ((unsigned)b) << 16; return v.f;
}
__device__ __forceinline__ u16 f2bf(float f) {
  union { float f; unsigned u; } v; v.f = f;
  unsigned r = v.u + 0x7FFFu + ((v.u >> 16) & 1u);
  return (u16)(r >> 16);
}

// async global->LDS, 16 B per lane. LDS dest = wave-uniform base + lane*16.
__device__ __forceinline__ void gload16(const u16* g, u16* l) {
  __builtin_amdgcn_global_load_lds(
      (const __attribute__((address_space(1))) unsigned int*)g,
      (__attribute__((address_space(3))) unsigned int*)l, 16, 0, 0);
}

// ---------------------------------------------------------------- fallback
__global__ __launch_bounds__(256) void zero_out_kernel(float* __restrict__ o, int n) {
  int i = blockIdx.x * 256 + threadIdx.x;
  if (i < n) o[i] = 0.f;
}

// ---------------------------------------------------------------- transposes
// generic z-batched: W[K,N] fp32 (stride sW per z) -> Wt[N,K] bf16 (stride sT)
__global__ __launch_bounds__(256) void transpose_cvt_b(
    const float* __restrict__ W, u16* __restrict__ Wt, int K, int N,
    long long sW, long long sT) {
  __shared__ float t[32][33];
  int z = blockIdx.z;
  W += (size_t)z * sW;
  Wt += (size_t)z * sT;
  int k0 = blockIdx.x * 32, n0 = blockIdx.y * 32;
  int tx = threadIdx.x, ty = threadIdx.y;   // 32 x 8
#pragma unroll
  for (int i = 0; i < 32; i += 8)
    t[ty + i][tx] = W[(size_t)(k0 + ty + i) * N + n0 + tx];
  __syncthreads();
#pragma unroll
  for (int i = 0; i < 32; i += 8)
    Wt[(size_t)(n0 + ty + i) * K + k0 + tx] = f2bf(t[tx][ty + i]);
}

// 9 per-layer 512x512 transposes (qsa,ksa,vsa) in ONE launch.
__global__ __launch_bounds__(256) void transpose_cvt_sa(
    const float* __restrict__ Wq_sa, const float* __restrict__ Wk_sa,
    const float* __restrict__ Wv_sa, u16* __restrict__ dst) {
  __shared__ float t[32][33];
  int z = blockIdx.z;
  int l = z / 3, wi = z % 3;
  const float* srcs[3] = {Wq_sa, Wk_sa, Wv_sa};
  const float* W = srcs[wi] + (size_t)l * 262144;
  u16* out = dst + ((size_t)l * 3 + wi) * 262144;
  int k0 = blockIdx.x * 32, n0 = blockIdx.y * 32;
  int tx = threadIdx.x, ty = threadIdx.y;
#pragma unroll
  for (int i = 0; i < 32; i += 8)
    t[ty + i][tx] = W[(size_t)(k0 + ty + i) * 512 + n0 + tx];
  __syncthreads();
#pragma unroll
  for (int i = 0; i < 32; i += 8)
    out[(size_t)(n0 + ty + i) * 512 + k0 + tx] = f2bf(t[tx][ty + i]);
}

// batched fp32->bf16 (ORIGINAL layout): z -> (l = z/5, s = z%5:
// 0 Wo_ac, 1 Wo_sa, 2 Wv_ac, 3 Wq_ac, 4 Wk_ac).  dst: [l][5][262144].
__global__ __launch_bounds__(256) void cvt_bf16_fifteen(
    const float* __restrict__ Wo_ac, const float* __restrict__ Wo_sa,
    const float* __restrict__ Wv_ac, const float* __restrict__ Wq_ac,
    const float* __restrict__ Wk_ac, u16* __restrict__ dst) {
  int z = blockIdx.z;
  int l = z / 5, s = z % 5;
  const float* bases[5] = {Wo_ac, Wo_sa, Wv_ac, Wq_ac, Wk_ac};
  const float* src = bases[s] + (size_t)l * 262144;
  u16* out = dst + ((size_t)l * 5 + s) * 262144;
  int i = blockIdx.x * 256 + threadIdx.x;
  if (i < 262144) out[i] = f2bf(src[i]);
}

// boa_eff[l][i] = bo_ac[l,i] + sum_k bv_ac[l,k] * Wo_ac[l,k,i]
__global__ __launch_bounds__(512) void boa_eff_kernel(
    const float* __restrict__ Wo_ac, const float* __restrict__ bo_ac,
    const float* __restrict__ bv_ac, float* __restrict__ out) {
  int l = blockIdx.x;
  int i = threadIdx.x;
  const float* Wo = Wo_ac + (size_t)l * 262144;
  float s = bo_ac[l * 512 + i];
  for (int k = 0; k < 512; k++) s += bv_ac[l * 512 + k] * Wo[(size_t)k * 512 + i];
  out[l * 512 + i] = s;
}

// combined bias: out[l][n] = bf[n] + boa_eff@Wf_top[:,n] + bos@Wf_bot[:,n]
__global__ __launch_bounds__(512) void bias_combine(
    const float* __restrict__ WfW, const float* __restrict__ bfW,
    const float* __restrict__ boa_eff, const float* __restrict__ bo_sa,
    float* __restrict__ out) {
  int l = blockIdx.x;
  const float* Wf = WfW + (size_t)l * 524288;
  int n = threadIdx.x;  // 512
  float s = bfW[l * 512 + n];
  for (int i = 0; i < 512; i++) s += boa_eff[l * 512 + i] * Wf[(size_t)i * 512 + n];
  for (int i = 0; i < 512; i++) s += bo_sa[l * 512 + i] * Wf[(size_t)(512 + i) * 512 + n];
  out[l * 512 + n] = s;
}

// ---------------------------------------------------------------- gemm128x256_p3
// Non-dmode variant: 2-buffer ring (48 KB LDS -> 3 blocks/CU), vmcnt(3).
// C[M,N](bf16, row-stride ldc) = A[M,K] @ Bt[N,K]^T + bias, opt relu.
// 128x256 tile, BK=32, 512 thr = 8 waves (2M x 4N), 64x64/wave.
__global__ __launch_bounds__(512, 4) void gemm128x256_p3(
    const u16* __restrict__ A1, const u16* __restrict__ A2, int lda, int ksplit,
    const u16* __restrict__ Bt, int ldb,
    const float* __restrict__ b0, const float* __restrict__ b1,
    const float* __restrict__ b2,
    u16* __restrict__ C, int ldc, int K, int relu, int nb) {
  __shared__ u16 smA[2][128 * 32];   // 2 x 8 KB
  __shared__ u16 smB[2][256 * 32];   // 2 x 16 KB
  int g = blockIdx.x;
  if ((gridDim.x & 7) == 0) g = (g & 7) * (gridDim.x >> 3) + (g >> 3);
  int m0 = (g / nb) * 128, n0 = (g % nb) * 256;
  int tid = threadIdx.x, lane = tid & 63, wid = tid >> 6;
  int wr = wid >> 2, wc = wid & 3;        // 2M x 4N wave grid
  int m_in = lane & 15, kq = lane >> 4;
  int sr = tid >> 2;                      // staging row 0..127
  int gsl = (((tid & 3) ^ ((sr >> 1) & 3)) * 8);  // pre-swizzled src col

  int offA[4], offB[4];
#pragma unroll
  for (int mf = 0; mf < 4; mf++) {
    int row = wr * 64 + mf * 16 + m_in;
    offA[mf] = row * 32 + ((kq ^ ((row >> 1) & 3)) * 8);
  }
#pragma unroll
  for (int nf = 0; nf < 4; nf++) {
    int row = wc * 64 + nf * 16 + m_in;
    offB[nf] = row * 32 + ((kq ^ ((row >> 1) & 3)) * 8);
  }
  f32x4 acc[4][4];
#pragma unroll
  for (int i = 0; i < 4; i++)
#pragma unroll
    for (int j = 0; j < 4; j++) acc[i][j] = (f32x4){0.f, 0.f, 0.f, 0.f};

  int nt = K >> 5;
  auto STAGE = [&](int b, int t) {
    int k0 = t * 32;
    const u16* Ap; int kk;
    if (k0 < ksplit) { Ap = A1; kk = k0; } else { Ap = A2; kk = k0 - ksplit; }
    gload16(&Ap[(size_t)(m0 + sr) * lda + kk + gsl], &smA[b][wid * 512]);
    gload16(&Bt[(size_t)(n0 + sr) * ldb + k0 + gsl], &smB[b][wid * 512]);
    gload16(&Bt[(size_t)(n0 + 128 + sr) * ldb + k0 + gsl],
            &smB[b][4096 + wid * 512]);
  };

  STAGE(0, 0);
  int cb = 0;
  for (int t = 0; t < nt; ++t) {
    int tn = t + 1 < nt ? t + 1 : t;   // clamp: restage into dead buffer
    STAGE(cb ^ 1, tn);
    asm volatile("s_waitcnt vmcnt(3)" ::: "memory");   // retire tile t's 3
    asm volatile("s_barrier" ::: "memory");
    const u16* la = &smA[cb][0];
    const u16* lb = &smB[cb][0];
    s16x8 a_[4], b_[4];
#pragma unroll
    for (int mf = 0; mf < 4; mf++) a_[mf] = *(const s16x8*)&la[offA[mf]];
#pragma unroll
    for (int nf = 0; nf < 4; nf++) b_[nf] = *(const s16x8*)&lb[offB[nf]];
    __builtin_amdgcn_s_setprio(1);
#pragma unroll
    for (int mf = 0; mf < 4; mf++)
#pragma unroll
      for (int nf = 0; nf < 4; nf++)
        acc[mf][nf] = __builtin_amdgcn_mfma_f32_16x16x32_bf16(
            a_[mf], b_[nf], acc[mf][nf], 0, 0, 0);
    __builtin_amdgcn_s_setprio(0);
    asm volatile("s_barrier" ::: "memory");
    cb ^= 1;
  }
  // C/D layout: col = lane&15, row = (lane>>4)*4 + reg   [m89/m91]
  int r0 = m0 + wr * 64 + (kq << 2);
#pragma unroll
  for (int mf = 0; mf < 4; mf++) {
#pragma unroll
    for (int nf = 0; nf < 4; nf++) {
      int col = n0 + wc * 64 + nf * 16 + m_in;
      const float* bp = (col < 512) ? b0 : (col < 1024 ? b1 : b2);
      float bv = bp ? bp[col & 511] : 0.f;
#pragma unroll
      for (int r = 0; r < 4; r++) {
        float v = acc[mf][nf][r] + bv;
        if (relu) v = fmaxf(v, 0.f);
        C[(size_t)(r0 + mf * 16 + r) * ldc + col] = f2bf(v);
      }
    }
  }
}

// ---------------------------------------------------------------- gemm128x256
// 3-ring 72 KB variant with dmode (fused series-decomp epilogue); for
// wcomb/W2 (dmode=1).  Structure proven R13-R19.
__global__ __launch_bounds__(512, 4) void gemm128x256(
    const u16* __restrict__ A1, const u16* __restrict__ A2, int lda, int ksplit,
    const u16* __restrict__ Bt, int ldb,
    const float* __restrict__ b0, const float* __restrict__ b1,
    const float* __restrict__ b2,
    u16* __restrict__ C, int ldc, int K, int relu, int nb, int dmode) {
  __shared__ u16 shm[36864];   // 73728 B: smA 3x4096 @0, smB 3x8192 @12288
  int g = blockIdx.x;
  if ((gridDim.x & 7) == 0) g = (g & 7) * (gridDim.x >> 3) + (g >> 3);
  int m0 = (g / nb) * 128, n0 = (g % nb) * 256;
  int tid = threadIdx.x, lane = tid & 63, wid = tid >> 6;
  int wr = wid >> 2, wc = wid & 3;        // 2M x 4N wave grid
  int m_in = lane & 15, kq = lane >> 4;
  int sr = tid >> 2;                      // staging row 0..127
  int gsl = (((tid & 3) ^ ((sr >> 1) & 3)) * 8);  // pre-swizzled src col

  int offA[4], offB[4];
#pragma unroll
  for (int mf = 0; mf < 4; mf++) {
    int row = wr * 64 + mf * 16 + m_in;
    offA[mf] = row * 32 + ((kq ^ ((row >> 1) & 3)) * 8);
  }
#pragma unroll
  for (int nf = 0; nf < 4; nf++) {
    int row = wc * 64 + nf * 16 + m_in;
    offB[nf] = row * 32 + ((kq ^ ((row >> 1) & 3)) * 8);
  }
  f32x4 acc[4][4];
#pragma unroll
  for (int i = 0; i < 4; i++)
#pragma unroll
    for (int j = 0; j < 4; j++) acc[i][j] = (f32x4){0.f, 0.f, 0.f, 0.f};

  int nt = K >> 5;
  auto STAGE = [&](int b, int t) {
    int k0 = t * 32;
    const u16* Ap; int kk;
    if (k0 < ksplit) { Ap = A1; kk = k0; } else { Ap = A2; kk = k0 - ksplit; }
    gload16(&Ap[(size_t)(m0 + sr) * lda + kk + gsl], &shm[b * 4096 + wid * 512]);
    gload16(&Bt[(size_t)(n0 + sr) * ldb + k0 + gsl],
            &shm[12288 + b * 8192 + wid * 512]);
    gload16(&Bt[(size_t)(n0 + 128 + sr) * ldb + k0 + gsl],
            &shm[12288 + b * 8192 + 4096 + wid * 512]);
  };

  STAGE(0, 0);
  STAGE(1, 1 < nt ? 1 : nt - 1);
  int cb = 0;
  for (int t = 0; t < nt; ++t) {
    int pf = t + 2 < nt ? t + 2 : nt - 1;
    int pb = cb + 2 >= 3 ? cb - 1 : cb + 2;
    STAGE(pb, pf);
    asm volatile("s_waitcnt vmcnt(6)" ::: "memory");   // retire tile t's 3
    asm volatile("s_barrier" ::: "memory");
    const u16* la = &shm[cb * 4096];
    const u16* lb = &shm[12288 + cb * 8192];
    s16x8 a_[4], b_[4];
#pragma unroll
    for (int mf = 0; mf < 4; mf++) a_[mf] = *(const s16x8*)&la[offA[mf]];
#pragma unroll
    for (int nf = 0; nf < 4; nf++) b_[nf] = *(const s16x8*)&lb[offB[nf]];
    __builtin_amdgcn_s_setprio(1);
#pragma unroll
    for (int mf = 0; mf < 4; mf++)
#pragma unroll
      for (int nf = 0; nf < 4; nf++)
        acc[mf][nf] = __builtin_amdgcn_mfma_f32_16x16x32_bf16(
            a_[mf], b_[nf], acc[mf][nf], 0, 0, 0);
    __builtin_amdgcn_s_setprio(0);
    asm volatile("s_barrier" ::: "memory");
    cb = cb + 1 >= 3 ? 0 : cb + 1;
  }
  // C/D layout: col = lane&15, row = (lane>>4)*4 + reg   [m89/m91]
  int r0 = m0 + wr * 64 + (kq << 2);
  if (dmode == 0) {
#pragma unroll
    for (int mf = 0; mf < 4; mf++) {
#pragma unroll
      for (int nf = 0; nf < 4; nf++) {
        int col = n0 + wc * 64 + nf * 16 + m_in;
        const float* bp = (col < 512) ? b0 : (col < 1024 ? b1 : b2);
        float bv = bp ? bp[col & 511] : 0.f;
#pragma unroll
        for (int r = 0; r < 4; r++) {
          float v = acc[mf][nf][r] + bv;
          if (relu) v = fmaxf(v, 0.f);
          C[(size_t)(r0 + mf * 16 + r) * ldc + col] = f2bf(v);
        }
      }
    }
  } else {
    // ---- fused series-decomp epilogue (N==512, ldc==512, C = X base) ----
    asm volatile("s_waitcnt vmcnt(0)" ::: "memory");
    __syncthreads();
    u16* wscr = &shm[wid * 4352];   // per-wave [64][68] bf16
    // phase 1: v = X + delta + bias -> LDS (bf16)
#pragma unroll
    for (int mf = 0; mf < 4; mf++) {
#pragma unroll
      for (int nf = 0; nf < 4; nf++) {
        int col = n0 + wc * 64 + nf * 16 + m_in;
        float bv = b0 ? b0[col & 511] : 0.f;
#pragma unroll
        for (int r = 0; r < 4; r++) {
          int row = r0 + mf * 16 + r;
          float xv = bf2f(C[(size_t)row * 512 + col]);
          wscr[(mf * 16 + (kq << 2) + r) * 68 + nf * 16 + m_in] =
              f2bf(xv + acc[mf][nf][r] + bv);
        }
      }
    }
    __syncthreads();
    // phase 2: per-lane column decomp (wave subtile = 1 sequence x 64 cols)
    int c = lane;
    int d = n0 + wc * 64 + c;
    int nseq = (m0 + wr * 64) >> 6;
    float v[64];
#pragma unroll
    for (int l = 0; l < 64; l++) v[l] = bf2f(wscr[l * 68 + c]);
    float s = 12.f * v[0];
#pragma unroll
    for (int t2 = 0; t2 <= 12; t2++) s += v[t2];
#pragma unroll
    for (int l = 0; l < 64; l++) {
      float out = v[l] - s * (1.f / 25.f);
      C[((size_t)nseq * 64 + l) * 512 + d] = f2bf(out);
      if (l < 63) {
        int add = l + 13; if (add > 63) add = 63;
        int sub = l - 12; if (sub < 0) sub = 0;
        s += v[add] - v[sub];
      }
    }
  }
}

// ---------------------------------------------------------------- gemm128p
// (R5-proven structure; + XCD remap; + y-batch strides for prep GEMMs)
__global__ __launch_bounds__(256) void gemm128p(
    const u16* __restrict__ A1, const u16* __restrict__ A2, int lda, int ksplit,
    const u16* __restrict__ Bt, int ldb,
    const float* __restrict__ b0, const float* __restrict__ b1,
    const float* __restrict__ b2,
    u16* __restrict__ C, int ldc, int K, int relu, int nb,
    long long syA, long long syB, long long syC) {
  __shared__ u16 sm[3][8192];   // per buffer: A[128][32] @0, B[128][32] @4096
  int zy = blockIdx.y;
  A1 += (size_t)zy * syA;
  A2 += (size_t)zy * syA;
  Bt += (size_t)zy * syB;
  C  += (size_t)zy * syC;
  int g = blockIdx.x;
  if ((gridDim.x & 7) == 0) g = (g & 7) * (gridDim.x >> 3) + (g >> 3);
  int m0 = (g / nb) * 128, n0 = (g % nb) * 128;
  int tid = threadIdx.x, lane = tid & 63, w = tid >> 6;
  int wr = w >> 1, wc = w & 1;
  int srow = w * 16 + (lane >> 2);
  int scol = (((lane & 3) ^ ((lane >> 3) & 3)) * 8);
  int m_in = lane & 15;
  int sgrp = lane >> 4;
  int offA[4], offB[4];
#pragma unroll
  for (int mf = 0; mf < 4; mf++) {
    int row = wr * 64 + mf * 16 + m_in;
    offA[mf] = row * 32 + ((sgrp ^ ((row >> 1) & 3)) * 8);
  }
#pragma unroll
  for (int nf = 0; nf < 4; nf++) {
    int row = wc * 64 + nf * 16 + m_in;
    offB[nf] = 4096 + row * 32 + ((sgrp ^ ((row >> 1) & 3)) * 8);
  }
  f32x4 acc[4][4];
#pragma unroll
  for (int i = 0; i < 4; i++)
#pragma unroll
    for (int j = 0; j < 4; j++) acc[i][j] = (f32x4){0.f, 0.f, 0.f, 0.f};

  int nt = K >> 5;
  auto STAGE = [&](int b, int t) {
    int k0 = t * 32;
    const u16* Ab; int kk;
    if (k0 < ksplit) { Ab = A1; kk = k0; } else { Ab = A2; kk = k0 - ksplit; }
    u16* base = &sm[b][0];
    gload16(&Ab[(size_t)(m0 + srow) * lda + kk + scol],      base + w * 512);
    gload16(&Ab[(size_t)(m0 + 64 + srow) * lda + kk + scol], base + 2048 + w * 512);
    gload16(&Bt[(size_t)(n0 + srow) * ldb + k0 + scol],      base + 4096 + w * 512);
    gload16(&Bt[(size_t)(n0 + 64 + srow) * ldb + k0 + scol], base + 6144 + w * 512);
  };

  STAGE(0, 0);
  STAGE(1, 1 < nt ? 1 : nt - 1);
  int cb = 0;
  for (int t = 0; t < nt; ++t) {
    int pf = t + 2 < nt ? t + 2 : nt - 1;
    int pb = cb + 2 >= 3 ? cb - 1 : cb + 2;
    STAGE(pb, pf);
    asm volatile("s_waitcnt vmcnt(8)" ::: "memory");
    asm volatile("s_barrier" ::: "memory");
    const u16* lb = &sm[cb][0];
    s16x8 a_[4], b_[4];
#pragma unroll
    for (int mf = 0; mf < 4; mf++) a_[mf] = *(const s16x8*)&lb[offA[mf]];
#pragma unroll
    for (int nf = 0; nf < 4; nf++) b_[nf] = *(const s16x8*)&lb[offB[nf]];
    __builtin_amdgcn_s_setprio(1);
#pragma unroll
    for (int mf = 0; mf < 4; mf++)
#pragma unroll
      for (int nf = 0; nf < 4; nf++)
        acc[mf][nf] = __builtin_amdgcn_mfma_f32_16x16x32_bf16(
            a_[mf], b_[nf], acc[mf][nf], 0, 0, 0);
    __builtin_amdgcn_s_setprio(0);
    asm volatile("s_barrier" ::: "memory");
    cb = cb + 1 >= 3 ? 0 : cb + 1;
  }
  int r0 = m0 + wr * 64 + (sgrp << 2);
  int cl = lane & 15;
#pragma unroll
  for (int mf = 0; mf < 4; mf++) {
#pragma unroll
    for (int nf = 0; nf < 4; nf++) {
      int col = n0 + wc * 64 + nf * 16 + cl;
      const float* bp = (col < 512) ? b0 : (col < 1024 ? b1 : b2);
      float bv = bp ? bp[col & 511] : 0.f;
#pragma unroll
      for (int r = 0; r < 4; r++) {
        float v = acc[mf][nf][r] + bv;
        if (relu) v = fmaxf(v, 0.f);
        C[(size_t)(r0 + mf * 16 + r) * ldc + col] = f2bf(v);
      }
    }
  }
}

// ---------------------------------------------------------------- gram + mc
// Per seq n: G[t][s] = sum_e Q[t,e]*K[s,e] (Q stride ldq, K stride ldk);
// MC[n,tau] = sum_t G[t][(t-tau)&63] / 512.
__global__ __launch_bounds__(256) void gram_mc_kernel(
    const u16* __restrict__ Q, int ldq, const u16* __restrict__ K, int ldk,
    float* __restrict__ MC) {
  __shared__ u16 lA[64][40];
  __shared__ u16 lB[64][40];
  __shared__ float red[64];
  int n = blockIdx.x;
  int tid = threadIdx.x, lane = tid & 63, w = tid >> 6;
  int sr = tid >> 2, scol = (tid & 3) * 8;
  if (tid < 64) red[tid] = 0.f;
  f32x4 acc[4];
#pragma unroll
  for (int i = 0; i < 4; i++) acc[i] = (f32x4){0.f, 0.f, 0.f, 0.f};
  size_t bq = (size_t)n * 64 * ldq;
  size_t bk = (size_t)n * 64 * ldk;
  for (int k0 = 0; k0 < 512; k0 += 32) {
    *(u16x8*)&lA[sr][scol] = *(const u16x8*)&Q[bq + (size_t)sr * ldq + k0 + scol];
    *(u16x8*)&lB[sr][scol] = *(const u16x8*)&K[bk + (size_t)sr * ldk + k0 + scol];
    __syncthreads();
    int ar = w * 16 + (lane & 15);
    int kk = (lane >> 4) * 8;
    s16x8 af = *(const s16x8*)&lA[ar][kk];
#pragma unroll
    for (int nb = 0; nb < 4; nb++) {
      s16x8 bfr = *(const s16x8*)&lB[nb * 16 + (lane & 15)][kk];
      acc[nb] = __builtin_amdgcn_mfma_f32_16x16x32_bf16(af, bfr, acc[nb], 0, 0, 0);
    }
    __syncthreads();
  }
  int row0 = w * 16 + ((lane >> 4) << 2);
  int cl = lane & 15;
#pragma unroll
  for (int nb = 0; nb < 4; nb++) {
    int col = nb * 16 + cl;
#pragma unroll
    for (int r = 0; r < 4; r++)
      atomicAdd(&red[(row0 + r - col) & 63], acc[nb][r]);
  }
  __syncthreads();
  if (tid < 64) MC[n * 64 + tid] = red[tid] * (1.f / 512.f);
}

// ---------------------------------------------------------------- inst norm
__global__ __launch_bounds__(256) void instnorm_kernel(
    const float* __restrict__ xe, float* __restrict__ MEANS, float* __restrict__ STDEV) {
  int n = blockIdx.x;           // b*21+c
  int b = n / 21, c = n % 21;
  int tid = threadIdx.x;
  float v0 = xe[((size_t)b * 512 + tid) * 21 + c];
  float v1 = xe[((size_t)b * 512 + tid + 256) * 21 + c];
  float s = v0 + v1, ss = v0 * v0 + v1 * v1;
  for (int o = 32; o; o >>= 1) { s += __shfl_down(s, o); ss += __shfl_down(ss, o); }
  __shared__ float rs[4], rss[4];
  if ((tid & 63) == 0) { rs[tid >> 6] = s; rss[tid >> 6] = ss; }
  __syncthreads();
  if (tid == 0) {
    s = rs[0] + rs[1] + rs[2] + rs[3];
    ss = rss[0] + rss[1] + rss[2] + rss[3];
    float mean = s * (1.f / 512.f);
    float var = ss * (1.f / 512.f) - mean * mean;
    MEANS[n] = mean;
    STDEV[n] = sqrtf(var + 1e-5f);
  }
}

// ---------------------------------------------------------------- pos emb
__global__ __launch_bounds__(256) void pe_kernel(float* __restrict__ PE) {
  int i = blockIdx.x * 256 + threadIdx.x;  // 32768
  int p = i >> 9, d = i & 511;
  int k = d >> 1;
  float freq = expf(-(float)(2 * k) * (9.210340371976184f / 512.f));
  float ang = (float)p * freq;
  PE[i] = (d & 1) ? cosf(ang) : sinf(ang);
}

// ---------------------------------------------------------------- patch embed
__global__ __launch_bounds__(256) void patch_kernel(
    const float* __restrict__ xe, const float* __restrict__ wv,
    const float* __restrict__ PE, const float* __restrict__ MEANS,
    const float* __restrict__ STDEV, u16* __restrict__ X) {
  __shared__ float pw[16][512];
  __shared__ float pat[8][16];
  int bx = blockIdx.x;
  int n = bx >> 3, pb = bx & 7;
  int b = n / 21, c = n % 21;
  int tid = threadIdx.x;
  float mean = MEANS[n], inv = 1.f / STDEV[n];
  for (int i = tid; i < 8192; i += 256) pw[i >> 9][i & 511] = wv[i];
  if (tid < 128) {
    int pp = tid >> 4, j = tid & 15;
    int l = (pb * 8 + pp) * 8 + j;
    if (l > 511) l = 511;                       // replication pad
    pat[pp][j] = (xe[((size_t)b * 512 + l) * 21 + c] - mean) * inv;
  }
  __syncthreads();
  for (int i = tid; i < 4096; i += 256) {
    int pp = i >> 9, d = i & 511;
    int p = pb * 8 + pp;
    float s = PE[p * 512 + d];
#pragma unroll
    for (int j = 0; j < 16; j++) s += pat[pp][j] * pw[j][d];
    X[((size_t)n * 64 + p) * 512 + d] = f2bf(s);
  }
}

// ---------------------------------------------------------------- topk + softw
__global__ __launch_bounds__(256) void topk_softw_kernel(
    const float* __restrict__ MC, int* __restrict__ TIDX, float* __restrict__ WSM) {
  __shared__ float g[256];
  __shared__ float gt[64];
  __shared__ int dly[4];
  int tid = threadIdx.x;
  int tau = tid & 63, part = tid >> 6;    // 4-way split over n
  float s = 0.f;
  for (int n = part * 168; n < (part + 1) * 168; n++) s += MC[n * 64 + tau];
  g[tid] = s;
  __syncthreads();
  if (tid < 64) gt[tid] = g[tid] + g[64 + tid] + g[128 + tid] + g[192 + tid];
  __syncthreads();
  if (tid == 0) {
    for (int j = 0; j < 4; j++) {
      int best = 0; float bv = -1e30f;
      for (int t = 0; t < 64; t++) if (gt[t] > bv) { bv = gt[t]; best = t; }
      dly[j] = best;
      TIDX[j] = best;
      gt[best] = -1e30f;
    }
  }
  __syncthreads();
  for (int n = tid; n < 672; n += 256) {
    float v[4], mx = -1e30f;
#pragma unroll
    for (int j = 0; j < 4; j++) { v[j] = MC[n * 64 + dly[j]]; mx = fmaxf(mx, v[j]); }
    float ssum = 0.f;
#pragma unroll
    for (int j = 0; j < 4; j++) { v[j] = __expf(v[j] - mx); ssum += v[j]; }
    float inv = 1.f / ssum;
#pragma unroll
    for (int j = 0; j < 4; j++) WSM[n * 4 + j] = v[j] * inv;
  }
}

// aggX[n,l,:] = sum_j w[n,j] * V[n,(l+delay_j)&63,:]  (V stride ldv, OUT ldo)
// Per-block sequence slab staged in LDS (64 KB): gather hits LDS, not HBM.
__global__ __launch_bounds__(256) void agg_kernel(
    const u16* __restrict__ V, int ldv, const float* __restrict__ WSM,
    const int* __restrict__ TIDX, u16* __restrict__ OUT, int ldo) {
  __shared__ u16 xs[64][512];   // 64 KB
  __shared__ float w[4];
  __shared__ int dly[4];
  int n = blockIdx.x;
  int tid = threadIdx.x;
  if (tid < 4) { w[tid] = WSM[n * 4 + tid]; dly[tid] = TIDX[tid]; }
  for (int i = tid; i < 64 * 64; i += 256) {
    int l = i >> 6, seg = (i & 63) * 8;
    *(u16x8*)&xs[l][seg] = *(const u16x8*)&V[((size_t)n * 64 + l) * ldv + seg];
  }
  __syncthreads();
  for (int i = tid; i < 64 * 512; i += 256) {
    int l = i >> 9, d = i & 511;
    float s = 0.f;
#pragma unroll
    for (int j = 0; j < 4; j++)
      s += w[j] * bf2f(xs[(l + dly[j]) & 63][d]);
    OUT[((size_t)n * 64 + l) * ldo + d] = f2bf(s);
  }
}

// ---------------------------------------------------------------- MFMA attention
__global__ __launch_bounds__(256) void attn_mfma(u16* __restrict__ QKV) {
  __shared__ u16 lq[64][72], lk[64][72], lvt[64][72], lp[64][72];
  int n = blockIdx.x >> 3, h = blockIdx.x & 7;
  size_t base = (size_t)n * 64 * 1536;
  int qo = h * 64, ko = 512 + h * 64, vo = 1024 + h * 64;
  int tid = threadIdx.x, lane = tid & 63, w = tid >> 6;
  int r = tid >> 2, c0 = (tid & 3) * 16;
  *(u16x8*)&lq[r][c0]     = *(const u16x8*)&QKV[base + (size_t)r * 1536 + qo + c0];
  *(u16x8*)&lq[r][c0 + 8] = *(const u16x8*)&QKV[base + (size_t)r * 1536 + qo + c0 + 8];
  *(u16x8*)&lk[r][c0]     = *(const u16x8*)&QKV[base + (size_t)r * 1536 + ko + c0];
  *(u16x8*)&lk[r][c0 + 8] = *(const u16x8*)&QKV[base + (size_t)r * 1536 + ko + c0 + 8];
  u16x8 v0 = *(const u16x8*)&QKV[base + (size_t)r * 1536 + vo + c0];
  u16x8 v1 = *(const u16x8*)&QKV[base + (size_t)r * 1536 + vo + c0 + 8];
#pragma unroll
  for (int j = 0; j < 8; j++) { lvt[c0 + j][r] = v0[j]; lvt[c0 + 8 + j][r] = v1[j]; }
  __syncthreads();
  int m_in = lane & 15, ks = (lane >> 4) * 8;
  int rq = lane >> 4;
  s16x8 aq0 = *(const s16x8*)&lq[w * 16 + m_in][ks];
  s16x8 aq1 = *(const s16x8*)&lq[w * 16 + m_in][32 + ks];
  f32x4 s4[4];
#pragma unroll
  for (int nf = 0; nf < 4; nf++) {
    s4[nf] = (f32x4){0.f, 0.f, 0.f, 0.f};
    s16x8 b0 = *(const s16x8*)&lk[nf * 16 + m_in][ks];
    s16x8 b1 = *(const s16x8*)&lk[nf * 16 + m_in][32 + ks];
    s4[nf] = __builtin_amdgcn_mfma_f32_16x16x32_bf16(aq0, b0, s4[nf], 0, 0, 0);
    s4[nf] = __builtin_amdgcn_mfma_f32_16x16x32_bf16(aq1, b1, s4[nf], 0, 0, 0);
  }
  float mx[4] = {-1e30f, -1e30f, -1e30f, -1e30f};
#pragma unroll
  for (int nf = 0; nf < 4; nf++)
#pragma unroll
    for (int r4 = 0; r4 < 4; r4++) {
      s4[nf][r4] *= 0.125f;
      mx[r4] = fmaxf(mx[r4], s4[nf][r4]);
    }
#pragma unroll
  for (int o = 1; o < 16; o <<= 1)
#pragma unroll
    for (int r4 = 0; r4 < 4; r4++) mx[r4] = fmaxf(mx[r4], __shfl_xor(mx[r4], o));
  float sum[4] = {0.f, 0.f, 0.f, 0.f};
#pragma unroll
  for (int nf = 0; nf < 4; nf++)
#pragma unroll
    for (int r4 = 0; r4 < 4; r4++) {
      float e = __expf(s4[nf][r4] - mx[r4]);
      s4[nf][r4] = e;
      sum[r4] += e;
    }
#pragma unroll
  for (int o = 1; o < 16; o <<= 1)
#pragma unroll
    for (int r4 = 0; r4 < 4; r4++) sum[r4] += __shfl_xor(sum[r4], o);
#pragma unroll
  for (int nf = 0; nf < 4; nf++)
#pragma unroll
    for (int r4 = 0; r4 < 4; r4++)
      lp[w * 16 + rq * 4 + r4][nf * 16 + m_in] = f2bf(s4[nf][r4] / sum[r4]);
  __syncthreads();
  s16x8 ap0 = *(const s16x8*)&lp[w * 16 + m_in][ks];
  s16x8 ap1 = *(const s16x8*)&lp[w * 16 + m_in][32 + ks];
#pragma unroll
  for (int nf = 0; nf < 4; nf++) {
    f32x4 o4 = (f32x4){0.f, 0.f, 0.f, 0.f};
    s16x8 b0 = *(const s16x8*)&lvt[nf * 16 + m_in][ks];
    s16x8 b1 = *(const s16x8*)&lvt[nf * 16 + m_in][32 + ks];
    o4 = __builtin_amdgcn_mfma_f32_16x16x32_bf16(ap0, b0, o4, 0, 0, 0);
    o4 = __builtin_amdgcn_mfma_f32_16x16x32_bf16(ap1, b1, o4, 0, 0, 0);
#pragma unroll
    for (int r4 = 0; r4 < 4; r4++)
      QKV[base + (size_t)(w * 16 + rq * 4 + r4) * 1536 + qo + nf * 16 + m_in] =
          f2bf(o4[r4]);
  }
}

// ---------------------------------------------------------------- batchnorm
__global__ __launch_bounds__(256) void bn_part(
    const u16* __restrict__ X, float* __restrict__ PS) {
  int ch = blockIdx.x, tid = threadIdx.x;
  float s1a = 0, s2a = 0, s1b = 0, s2b = 0;
  size_t base = (size_t)ch * 128 * 512;
  for (int r = 0; r < 128; r++) {
    float a = bf2f(X[base + (size_t)r * 512 + tid]);
    float b = bf2f(X[base + (size_t)r * 512 + tid + 256]);
    s1a += a; s2a += a * a; s1b += b; s2b += b * b;
  }
  PS[(size_t)(ch * 2 + 0) * 512 + tid] = s1a;
  PS[(size_t)(ch * 2 + 0) * 512 + tid + 256] = s1b;
  PS[(size_t)(ch * 2 + 1) * 512 + tid] = s2a;
  PS[(size_t)(ch * 2 + 1) * 512 + tid + 256] = s2b;
}

__global__ __launch_bounds__(256) void bn_final(
    const float* __restrict__ PS, const float* __restrict__ g,
    const float* __restrict__ b, float* __restrict__ SCALE, float* __restrict__ SHIFT) {
  int d = blockIdx.x * 256 + threadIdx.x;   // < 512
  float s = 0, ss = 0;
  for (int c = 0; c < 336; c++) {
    s += PS[(size_t)(c * 2) * 512 + d];
    ss += PS[(size_t)(c * 2 + 1) * 512 + d];
  }
  float mu = s * (1.f / 43008.f);
  float var = ss * (1.f / 43008.f) - mu * mu;
  float inv = 1.f / sqrtf(var + 1e-5f);
  float sc = g[d] * inv;
  SCALE[d] = sc;
  SHIFT[d] = b[d] - mu * sc;
}

// ---------------------------------------------------------------- bn transpose
__global__ __launch_bounds__(256) void bn_transpose_kernel(
    const u16* __restrict__ X, const float* __restrict__ SCALE,
    const float* __restrict__ SHIFT, u16* __restrict__ ENC) {
  __shared__ u16 t[64][72];
  int n = blockIdx.x >> 3, dc = (blockIdx.x & 7) * 64;
  int tid = threadIdx.x;
  for (int i = tid; i < 4096; i += 256) {
    int p = i >> 6, d = i & 63;
    float v = bf2f(X[((size_t)n * 64 + p) * 512 + dc + d]) * SCALE[dc + d] + SHIFT[dc + d];
    t[p][d] = f2bf(v);
  }
  __syncthreads();
  for (int i = tid; i < 4096; i += 256) {
    int d = i >> 6, p = i & 63;
    ENC[(size_t)n * 32768 + (size_t)(dc + d) * 64 + p] = t[p][d];
  }
}

// ---------------------------------------------------------------- head GEMM
// PART[kc][672][96] partial over 32 K-chunks of 1024
__global__ __launch_bounds__(256) void head_gemm(
    const u16* __restrict__ ENC, const u16* __restrict__ Wht,
    float* __restrict__ PART) {
  __shared__ u16 lA[64][40];
  __shared__ u16 lB[96][40];
  int bm = blockIdx.x;   // 0..10
  int kc = blockIdx.y;   // 0..31
  int tid = threadIdx.x, lane = tid & 63, w = tid >> 6;
  int sr = tid >> 2, sc0 = (tid & 3) * 8;
  f32x4 acc[6];
#pragma unroll
  for (int i = 0; i < 6; i++) acc[i] = (f32x4){0.f, 0.f, 0.f, 0.f};
  for (int kk0 = 0; kk0 < 1024; kk0 += 32) {
    int k0 = kc * 1024 + kk0;
    *(u16x8*)&lA[sr][sc0] =
        *(const u16x8*)&ENC[(size_t)(bm * 64 + sr) * 32768 + k0 + sc0];
    for (int i = tid; i < 96 * 4; i += 256) {
      int rB = i >> 2, seg = (i & 3) * 8;
      *(u16x8*)&lB[rB][seg] = *(const u16x8*)&Wht[(size_t)rB * 32768 + k0 + seg];
    }
    __syncthreads();
    int ar = w * 16 + (lane & 15);
    int kk = (lane >> 4) * 8;
    s16x8 af = *(const s16x8*)&lA[ar][kk];
#pragma unroll
    for (int nb = 0; nb < 6; nb++) {
      s16x8 bfr = *(const s16x8*)&lB[nb * 16 + (lane & 15)][kk];
      acc[nb] = __builtin_amdgcn_mfma_f32_16x16x32_bf16(af, bfr, acc[nb], 0, 0, 0);
    }
    __syncthreads();
  }
  int rb = bm * 64 + w * 16 + ((lane >> 4) << 2);
  int cl = lane & 15;
#pragma unroll
  for (int nb = 0; nb < 6; nb++) {
    int col = nb * 16 + cl;
#pragma unroll
    for (int r = 0; r < 4; r++) {
      int row = rb + r;
      if (row < 672) PART[((size_t)kc * 672 + row) * 96 + col] = acc[nb][r];
    }
  }
}

__global__ __launch_bounds__(256) void head_reduce(
    const float* __restrict__ PART, const float* __restrict__ bh,
    const float* __restrict__ STDEV, const float* __restrict__ MEANS,
    float* __restrict__ OUT) {
  int i = blockIdx.x * 256 + threadIdx.x;
  if (i >= 672 * 96) return;
  int n = i / 96, r = i % 96;
  float s = bh[r];
  for (int kc = 0; kc < 32; kc++) s += PART[((size_t)kc * 672 + n) * 96 + r];
  int b = n / 21, c = n % 21;
  OUT[((size_t)b * 96 + r) * 21 + c] = s * STDEV[n] + MEANS[n];
}

// ============================================================================
extern "C" void kernel_launch(void* const* d_in, const int* in_sizes, int n_in,
                              void* d_out, int out_size, void* d_ws, size_t ws_size,
                              hipStream_t stream) {
  const float* x_enc = (const float*)d_in[0];
  const float* w_val = (const float*)d_in[1];
  const float* Wq_ac = (const float*)d_in[2];
  const float* Wk_ac = (const float*)d_in[3];
  const float* Wv_ac = (const float*)d_in[4];
  const float* Wo_ac = (const float*)d_in[5];
  const float* bq_ac = (const float*)d_in[6];
  const float* bk_ac = (const float*)d_in[7];
  const float* bv_ac = (const float*)d_in[8];
  const float* bo_ac = (const float*)d_in[9];
  const float* Wq_sa = (const float*)d_in[10];
  const float* Wk_sa = (const float*)d_in[11];
  const float* Wv_sa = (const float*)d_in[12];
  const float* Wo_sa = (const float*)d_in[13];
  const float* bq_sa = (const float*)d_in[14];
  const float* bk_sa = (const float*)d_in[15];
  const float* bv_sa = (const float*)d_in[16];
  const float* bo_sa = (const float*)d_in[17];
  const float* WfW   = (const float*)d_in[18];
  const float* bfW   = (const float*)d_in[19];
  const float* W1    = (const float*)d_in[20];
  const float* W2    = (const float*)d_in[21];
  const float* bn_g  = (const float*)d_in[22];
  const float* bn_b  = (const float*)d_in[23];
  const float* W_head = (const float*)d_in[24];
  const float* b_head = (const float*)d_in[25];
  (void)in_sizes; (void)n_in; (void)out_size;
  (void)bq_ac; (void)bk_ac;   // provably cancel in mean_corr top-k/softmax

  // ---- workspace carve-up (~220 MB)
  char* wsp = (char*)d_ws;
  size_t off = 0;
  auto alloc = [&](size_t bytes) -> void* {
    void* p = wsp + off;
    off += (bytes + 255) & ~(size_t)255;
    return p;
  };
  u16* X    = (u16*)alloc((size_t)MROWS * 512 * 2);
  u16* Q3   = (u16*)alloc((size_t)MROWS * 1536 * 2);   // 3 column slices
  u16* SIX   = (u16*)alloc((size_t)3 * 3 * 262144 * 2);  // qsa,ksa,vsa ^T
  u16* W1T   = (u16*)alloc((size_t)3 * 1048576 * 2);
  u16* W2T   = (u16*)alloc((size_t)3 * 1048576 * 2);
  u16* WFT   = (u16*)alloc((size_t)3 * 524288 * 2);
  u16* WORIG = (u16*)alloc((size_t)3 * 5 * 262144 * 2);  // [l][woac|wosa|wvac|wqac|wkac]
  u16* WCOMB = (u16*)alloc((size_t)3 * 524288 * 2);
  u16* WQKT  = (u16*)alloc((size_t)3 * 262144 * 2);      // (Wq·Wk^T)^T per layer
  u16* WHT   = (u16*)alloc((size_t)3145728 * 2);
  u16* TMP   = (u16*)alloc((size_t)3 * 262144 * 2);
  float* PE = (float*)alloc((size_t)32768 * 4);
  float* MEANS = (float*)alloc(672 * 4);
  float* STDEV = (float*)alloc(672 * 4);
  float* MC = (float*)alloc(672 * 64 * 4);
  int* TIDX = (int*)alloc(4 * 4);
  float* WSM = (float*)alloc(672 * 4 * 4);
  float* BNP = (float*)alloc((size_t)336 * 1024 * 4);
  float* SCALE = (float*)alloc(512 * 4);
  float* SHIFT = (float*)alloc(512 * 4);
  float* BOAE = (float*)alloc(3 * 512 * 4);
  float* BCOMB = (float*)alloc(3 * 512 * 4);
  u16* C0 = Q3;          // cols    0..511
  u16* C1 = Q3 + 512;    // cols  512..1023
  u16* C2 = Q3 + 1024;   // cols 1024..1535
  u16* HBUF = Q3;                                  // [21504][2048] = 88 MB
  u16* ENC  = Q3;                                  // head: [672][32768]
  float* HEADP = (float*)X;                        // head partials overlay X (8.3 MB)

  if (off > ws_size) {
    zero_out_kernel<<<252, 256, 0, stream>>>((float*)d_out, 672 * 96);
    return;
  }

  // ---- weight prep
  transpose_cvt_sa<<<dim3(16, 16, 9), dim3(32, 8), 0, stream>>>(
      Wq_sa, Wk_sa, Wv_sa, SIX);
  transpose_cvt_b<<<dim3(16, 64, 3), dim3(32, 8), 0, stream>>>(
      W1, W1T, 512, 2048, 1048576, 1048576);
  transpose_cvt_b<<<dim3(64, 16, 3), dim3(32, 8), 0, stream>>>(
      W2, W2T, 2048, 512, 1048576, 1048576);
  transpose_cvt_b<<<dim3(32, 16, 3), dim3(32, 8), 0, stream>>>(
      WfW, WFT, 1024, 512, 524288, 524288);
  transpose_cvt_b<<<dim3(1024, 3, 1), dim3(32, 8), 0, stream>>>(
      W_head, WHT, 32768, 96, 0, 0);
  cvt_bf16_fifteen<<<dim3(1024, 1, 15), 256, 0, stream>>>(
      Wo_ac, Wo_sa, Wv_ac, Wq_ac, Wk_ac, WORIG);
  boa_eff_kernel<<<3, 512, 0, stream>>>(Wo_ac, bo_ac, bv_ac, BOAE);
  bias_combine<<<3, 512, 0, stream>>>(WfW, bfW, BOAE, bo_sa, BCOMB);
  // prep GEMMs, y-batched over layers (4 launches):
  gemm128p<<<dim3(16, 3), 256, 0, stream>>>(
      WFT, WFT, 1024, 512, WORIG, 512, nullptr, nullptr, nullptr,
      TMP, 512, 512, 0, 4, 524288, 5 * 262144, 262144);
  gemm128p<<<dim3(16, 3), 256, 0, stream>>>(
      TMP, TMP, 512, 512, WORIG + 2 * 262144, 512, nullptr, nullptr, nullptr,
      WCOMB, 1024, 512, 0, 4, 262144, 5 * 262144, 524288);
  gemm128p<<<dim3(16, 3), 256, 0, stream>>>(
      WFT + 512, WFT + 512, 1024, 512, WORIG + 262144, 512,
      nullptr, nullptr, nullptr, WCOMB + 512, 1024, 512, 0, 4,
      524288, 5 * 262144, 524288);
  gemm128p<<<dim3(16, 3), 256, 0, stream>>>(
      WORIG + 4 * 262144, WORIG + 4 * 262144, 512, 512,
      WORIG + 3 * 262144, 512, nullptr, nullptr, nullptr,
      WQKT, 512, 512, 0, 4, 5 * 262144, 5 * 262144, 262144);

  // ---- front end
  instnorm_kernel<<<672, 256, 0, stream>>>(x_enc, MEANS, STDEV);
  pe_kernel<<<128, 256, 0, stream>>>(PE);
  patch_kernel<<<672 * 8, 256, 0, stream>>>(x_enc, w_val, PE, MEANS, STDEV, X);

  // big gemm helpers: p3 = 2-ring 3 blk/CU (no dmode); gbig = 3-ring + dmode
  auto gp3 = [&](const u16* A1, const u16* A2, int lda, int ksplit,
                 const u16* Bt, int ldb, const float* b0, const float* b1,
                 const float* b2, u16* C, int ldc, int M, int N, int K,
                 int relu) {
    int nb = N / 256;
    if (nb < 1) nb = 1;
    gemm128x256_p3<<<(M / 128) * nb, 512, 0, stream>>>(
        A1, A2, lda, ksplit, Bt, ldb, b0, b1, b2, C, ldc, K, relu, nb);
  };
  auto gbig = [&](const u16* A1, const u16* A2, int lda, int ksplit,
                  const u16* Bt, int ldb, const float* b0, const float* b1,
                  const float* b2, u16* C, int ldc, int M, int N, int K,
                  int relu, int dmode) {
    int nb = N / 256;
    if (nb < 1) nb = 1;
    gemm128x256<<<(M / 128) * nb, 512, 0, stream>>>(
        A1, A2, lda, ksplit, Bt, ldb, b0, b1, b2, C, ldc, K, relu, nb, dmode);
  };

  // ---- encoder layers
  for (int l = 0; l < 3; l++) {
    const u16* qkv_sa = SIX + (size_t)l * 3 * 262144;        // [1536][512]
    const u16* wqkt   = WQKT + (size_t)l * 262144;
    const u16* w1     = W1T + (size_t)l * 1048576;
    const u16* w2     = W2T + (size_t)l * 1048576;
    const u16* wcomb  = WCOMB + (size_t)l * 524288;
    // SA: fused QKV (N=1536) -> Q3 [q|k|v]
    gp3(X, X, 512, 512, qkv_sa, 512, bq_sa + l * 512, bk_sa + l * 512,
        bv_sa + l * 512, Q3, 1536, MROWS, 1536, 512, 0);
    attn_mfma<<<5376, 256, 0, stream>>>(Q3);                    // attnout -> C0
    // AC: Y = X @ (Wq·Wk^T)  (N=512, biases provably cancel) -> C1
    gp3(X, X, 512, 512, wqkt, 512, nullptr, nullptr, nullptr,
        C1, 1536, MROWS, 512, 512, 0);
    gram_mc_kernel<<<672, 256, 0, stream>>>(C1, 1536, X, 512, MC);
    topk_softw_kernel<<<1, 256, 0, stream>>>(MC, TIDX, WSM);
    // aggX from X directly (Wv fold), LDS-staged gather -> C2
    agg_kernel<<<672, 256, 0, stream>>>(X, 512, WSM, TIDX, C2, 1536);
    // fused+decomp: X <- decomp(X + aggX@WcombA + attnout@WcombS + bcomb)
    gbig(C2, C0, 1536, 512, wcomb, 1024, BCOMB + l * 512, nullptr, nullptr,
         X, 512, MROWS, 512, 1024, 0, 1);
    // FFN in 2 M-chunks of 21504; W2 fused with decomp (writes X in place)
    for (int c = 0; c < 2; c++) {
      const u16* Xc = X + (size_t)c * 21504 * 512;
      u16* Xcw = X + (size_t)c * 21504 * 512;
      gp3(Xc, Xc, 512, 512, w1, 512, nullptr, nullptr, nullptr,
          HBUF, 2048, 21504, 2048, 512, 1);
      gbig(HBUF, HBUF, 2048, 2048, w2, 2048, nullptr, nullptr, nullptr,
           Xcw, 512, 21504, 512, 2048, 0, 1);
    }
  }

  // ---- batchnorm + head
  bn_part<<<336, 256, 0, stream>>>(X, BNP);
  bn_final<<<2, 256, 0, stream>>>(BNP, bn_g, bn_b, SCALE, SHIFT);
  bn_transpose_kernel<<<672 * 8, 256, 0, stream>>>(X, SCALE, SHIFT, ENC);
  head_gemm<<<dim3(11, 32), 256, 0, stream>>>(ENC, WHT, HEADP);
  head_reduce<<<252, 256, 0, stream>>>(HEADP, b_head, STDEV, MEANS, (float*)d_out);
}

// Round 21
// 1944.222 us; speedup vs baseline: 1.0124x; 1.0124x over previous
//
#include <hip/hip_runtime.h>
#include <math.h>

// ============================================================================
// PatchTST/Autoformer hybrid forward on MI355X (gfx950).  Round 21 = R19
// (best verified; R20's 2-ring p3 variant regressed and was reverted).
//  - agg_kernel: per-sequence X slab staged in LDS (64 KB); 4-delay gather
//    hits LDS instead of HBM.
//  - head_gemm: K-split 32 chunks (grid 352 blocks >= CU count).
//  - decomp-fused GEMM epilogue (dmode=1); folds #1,#2,#3.
//  - gemm128x256 (3-ring, vmcnt(6), XOR swizzle, 2 blk/CU) for all big GEMMs.
// ============================================================================

typedef unsigned short u16;
typedef short s16x8 __attribute__((ext_vector_type(8)));
typedef u16 u16x8 __attribute__((ext_vector_type(8)));
typedef float f32x4 __attribute__((ext_vector_type(4)));

#define MROWS 43008   // 672 * 64
#define NSEQ  672

__device__ __forceinline__ float bf2f(u16 b) {
  union { unsigned u; float f; } v; v.u = ((unsigned)b) << 16; return v.f;
}
__device__ __forceinline__ u16 f2bf(float f) {
  union { float f; unsigned u; } v; v.f = f;
  unsigned r = v.u + 0x7FFFu + ((v.u >> 16) & 1u);
  return (u16)(r >> 16);
}

// async global->LDS, 16 B per lane. LDS dest = wave-uniform base + lane*16.
__device__ __forceinline__ void gload16(const u16* g, u16* l) {
  __builtin_amdgcn_global_load_lds(
      (const __attribute__((address_space(1))) unsigned int*)g,
      (__attribute__((address_space(3))) unsigned int*)l, 16, 0, 0);
}

// ---------------------------------------------------------------- fallback
__global__ __launch_bounds__(256) void zero_out_kernel(float* __restrict__ o, int n) {
  int i = blockIdx.x * 256 + threadIdx.x;
  if (i < n) o[i] = 0.f;
}

// ---------------------------------------------------------------- transposes
// generic z-batched: W[K,N] fp32 (stride sW per z) -> Wt[N,K] bf16 (stride sT)
__global__ __launch_bounds__(256) void transpose_cvt_b(
    const float* __restrict__ W, u16* __restrict__ Wt, int K, int N,
    long long sW, long long sT) {
  __shared__ float t[32][33];
  int z = blockIdx.z;
  W += (size_t)z * sW;
  Wt += (size_t)z * sT;
  int k0 = blockIdx.x * 32, n0 = blockIdx.y * 32;
  int tx = threadIdx.x, ty = threadIdx.y;   // 32 x 8
#pragma unroll
  for (int i = 0; i < 32; i += 8)
    t[ty + i][tx] = W[(size_t)(k0 + ty + i) * N + n0 + tx];
  __syncthreads();
#pragma unroll
  for (int i = 0; i < 32; i += 8)
    Wt[(size_t)(n0 + ty + i) * K + k0 + tx] = f2bf(t[tx][ty + i]);
}

// 9 per-layer 512x512 transposes (qsa,ksa,vsa) in ONE launch.
__global__ __launch_bounds__(256) void transpose_cvt_sa(
    const float* __restrict__ Wq_sa, const float* __restrict__ Wk_sa,
    const float* __restrict__ Wv_sa, u16* __restrict__ dst) {
  __shared__ float t[32][33];
  int z = blockIdx.z;
  int l = z / 3, wi = z % 3;
  const float* srcs[3] = {Wq_sa, Wk_sa, Wv_sa};
  const float* W = srcs[wi] + (size_t)l * 262144;
  u16* out = dst + ((size_t)l * 3 + wi) * 262144;
  int k0 = blockIdx.x * 32, n0 = blockIdx.y * 32;
  int tx = threadIdx.x, ty = threadIdx.y;
#pragma unroll
  for (int i = 0; i < 32; i += 8)
    t[ty + i][tx] = W[(size_t)(k0 + ty + i) * 512 + n0 + tx];
  __syncthreads();
#pragma unroll
  for (int i = 0; i < 32; i += 8)
    out[(size_t)(n0 + ty + i) * 512 + k0 + tx] = f2bf(t[tx][ty + i]);
}

// batched fp32->bf16 (ORIGINAL layout): z -> (l = z/5, s = z%5:
// 0 Wo_ac, 1 Wo_sa, 2 Wv_ac, 3 Wq_ac, 4 Wk_ac).  dst: [l][5][262144].
__global__ __launch_bounds__(256) void cvt_bf16_fifteen(
    const float* __restrict__ Wo_ac, const float* __restrict__ Wo_sa,
    const float* __restrict__ Wv_ac, const float* __restrict__ Wq_ac,
    const float* __restrict__ Wk_ac, u16* __restrict__ dst) {
  int z = blockIdx.z;
  int l = z / 5, s = z % 5;
  const float* bases[5] = {Wo_ac, Wo_sa, Wv_ac, Wq_ac, Wk_ac};
  const float* src = bases[s] + (size_t)l * 262144;
  u16* out = dst + ((size_t)l * 5 + s) * 262144;
  int i = blockIdx.x * 256 + threadIdx.x;
  if (i < 262144) out[i] = f2bf(src[i]);
}

// boa_eff[l][i] = bo_ac[l,i] + sum_k bv_ac[l,k] * Wo_ac[l,k,i]
__global__ __launch_bounds__(512) void boa_eff_kernel(
    const float* __restrict__ Wo_ac, const float* __restrict__ bo_ac,
    const float* __restrict__ bv_ac, float* __restrict__ out) {
  int l = blockIdx.x;
  int i = threadIdx.x;
  const float* Wo = Wo_ac + (size_t)l * 262144;
  float s = bo_ac[l * 512 + i];
  for (int k = 0; k < 512; k++) s += bv_ac[l * 512 + k] * Wo[(size_t)k * 512 + i];
  out[l * 512 + i] = s;
}

// combined bias: out[l][n] = bf[n] + boa_eff@Wf_top[:,n] + bos@Wf_bot[:,n]
__global__ __launch_bounds__(512) void bias_combine(
    const float* __restrict__ WfW, const float* __restrict__ bfW,
    const float* __restrict__ boa_eff, const float* __restrict__ bo_sa,
    float* __restrict__ out) {
  int l = blockIdx.x;
  const float* Wf = WfW + (size_t)l * 524288;
  int n = threadIdx.x;  // 512
  float s = bfW[l * 512 + n];
  for (int i = 0; i < 512; i++) s += boa_eff[l * 512 + i] * Wf[(size_t)i * 512 + n];
  for (int i = 0; i < 512; i++) s += bo_sa[l * 512 + i] * Wf[(size_t)(512 + i) * 512 + n];
  out[l * 512 + n] = s;
}

// ---------------------------------------------------------------- gemm128x256
// C[M,N](bf16, row-stride ldc) = A[M,K] @ Bt[N,K]^T + bias, opt relu.
// 128x256 tile, BK=32, 512 thr = 8 waves (2M x 4N), 64x64/wave.
// 3-buffer ring, prefetch depth 2, vmcnt(6), raw barriers, XOR swizzle
// (both sides), setprio.  LDS 72 KB -> 2 blocks/CU.
// dmode=1 (requires N==512, ldc==512, relu==0): fused series-decomp epilogue.
__global__ __launch_bounds__(512, 4) void gemm128x256(
    const u16* __restrict__ A1, const u16* __restrict__ A2, int lda, int ksplit,
    const u16* __restrict__ Bt, int ldb,
    const float* __restrict__ b0, const float* __restrict__ b1,
    const float* __restrict__ b2,
    u16* __restrict__ C, int ldc, int K, int relu, int nb, int dmode) {
  __shared__ u16 shm[36864];   // 73728 B: smA 3x4096 @0, smB 3x8192 @12288
  int g = blockIdx.x;
  if ((gridDim.x & 7) == 0) g = (g & 7) * (gridDim.x >> 3) + (g >> 3);
  int m0 = (g / nb) * 128, n0 = (g % nb) * 256;
  int tid = threadIdx.x, lane = tid & 63, wid = tid >> 6;
  int wr = wid >> 2, wc = wid & 3;        // 2M x 4N wave grid
  int m_in = lane & 15, kq = lane >> 4;
  int sr = tid >> 2;                      // staging row 0..127
  int gsl = (((tid & 3) ^ ((sr >> 1) & 3)) * 8);  // pre-swizzled src col

  int offA[4], offB[4];
#pragma unroll
  for (int mf = 0; mf < 4; mf++) {
    int row = wr * 64 + mf * 16 + m_in;
    offA[mf] = row * 32 + ((kq ^ ((row >> 1) & 3)) * 8);
  }
#pragma unroll
  for (int nf = 0; nf < 4; nf++) {
    int row = wc * 64 + nf * 16 + m_in;
    offB[nf] = row * 32 + ((kq ^ ((row >> 1) & 3)) * 8);
  }
  f32x4 acc[4][4];
#pragma unroll
  for (int i = 0; i < 4; i++)
#pragma unroll
    for (int j = 0; j < 4; j++) acc[i][j] = (f32x4){0.f, 0.f, 0.f, 0.f};

  int nt = K >> 5;
  auto STAGE = [&](int b, int t) {
    int k0 = t * 32;
    const u16* Ap; int kk;
    if (k0 < ksplit) { Ap = A1; kk = k0; } else { Ap = A2; kk = k0 - ksplit; }
    gload16(&Ap[(size_t)(m0 + sr) * lda + kk + gsl], &shm[b * 4096 + wid * 512]);
    gload16(&Bt[(size_t)(n0 + sr) * ldb + k0 + gsl],
            &shm[12288 + b * 8192 + wid * 512]);
    gload16(&Bt[(size_t)(n0 + 128 + sr) * ldb + k0 + gsl],
            &shm[12288 + b * 8192 + 4096 + wid * 512]);
  };

  STAGE(0, 0);
  STAGE(1, 1 < nt ? 1 : nt - 1);
  int cb = 0;
  for (int t = 0; t < nt; ++t) {
    int pf = t + 2 < nt ? t + 2 : nt - 1;
    int pb = cb + 2 >= 3 ? cb - 1 : cb + 2;
    STAGE(pb, pf);
    asm volatile("s_waitcnt vmcnt(6)" ::: "memory");   // retire tile t's 3
    asm volatile("s_barrier" ::: "memory");
    const u16* la = &shm[cb * 4096];
    const u16* lb = &shm[12288 + cb * 8192];
    s16x8 a_[4], b_[4];
#pragma unroll
    for (int mf = 0; mf < 4; mf++) a_[mf] = *(const s16x8*)&la[offA[mf]];
#pragma unroll
    for (int nf = 0; nf < 4; nf++) b_[nf] = *(const s16x8*)&lb[offB[nf]];
    __builtin_amdgcn_s_setprio(1);
#pragma unroll
    for (int mf = 0; mf < 4; mf++)
#pragma unroll
      for (int nf = 0; nf < 4; nf++)
        acc[mf][nf] = __builtin_amdgcn_mfma_f32_16x16x32_bf16(
            a_[mf], b_[nf], acc[mf][nf], 0, 0, 0);
    __builtin_amdgcn_s_setprio(0);
    asm volatile("s_barrier" ::: "memory");
    cb = cb + 1 >= 3 ? 0 : cb + 1;
  }
  // C/D layout: col = lane&15, row = (lane>>4)*4 + reg   [m89/m91]
  int r0 = m0 + wr * 64 + (kq << 2);
  if (dmode == 0) {
#pragma unroll
    for (int mf = 0; mf < 4; mf++) {
#pragma unroll
      for (int nf = 0; nf < 4; nf++) {
        int col = n0 + wc * 64 + nf * 16 + m_in;
        const float* bp = (col < 512) ? b0 : (col < 1024 ? b1 : b2);
        float bv = bp ? bp[col & 511] : 0.f;
#pragma unroll
        for (int r = 0; r < 4; r++) {
          float v = acc[mf][nf][r] + bv;
          if (relu) v = fmaxf(v, 0.f);
          C[(size_t)(r0 + mf * 16 + r) * ldc + col] = f2bf(v);
        }
      }
    }
  } else {
    // ---- fused series-decomp epilogue (N==512, ldc==512, C = X base) ----
    asm volatile("s_waitcnt vmcnt(0)" ::: "memory");
    __syncthreads();
    u16* wscr = &shm[wid * 4352];   // per-wave [64][68] bf16
    // phase 1: v = X + delta + bias -> LDS (bf16)
#pragma unroll
    for (int mf = 0; mf < 4; mf++) {
#pragma unroll
      for (int nf = 0; nf < 4; nf++) {
        int col = n0 + wc * 64 + nf * 16 + m_in;
        float bv = b0 ? b0[col & 511] : 0.f;
#pragma unroll
        for (int r = 0; r < 4; r++) {
          int row = r0 + mf * 16 + r;
          float xv = bf2f(C[(size_t)row * 512 + col]);
          wscr[(mf * 16 + (kq << 2) + r) * 68 + nf * 16 + m_in] =
              f2bf(xv + acc[mf][nf][r] + bv);
        }
      }
    }
    __syncthreads();
    // phase 2: per-lane column decomp (wave subtile = 1 sequence x 64 cols)
    int c = lane;
    int d = n0 + wc * 64 + c;
    int nseq = (m0 + wr * 64) >> 6;
    float v[64];
#pragma unroll
    for (int l = 0; l < 64; l++) v[l] = bf2f(wscr[l * 68 + c]);
    float s = 12.f * v[0];
#pragma unroll
    for (int t2 = 0; t2 <= 12; t2++) s += v[t2];
#pragma unroll
    for (int l = 0; l < 64; l++) {
      float out = v[l] - s * (1.f / 25.f);
      C[((size_t)nseq * 64 + l) * 512 + d] = f2bf(out);
      if (l < 63) {
        int add = l + 13; if (add > 63) add = 63;
        int sub = l - 12; if (sub < 0) sub = 0;
        s += v[add] - v[sub];
      }
    }
  }
}

// ---------------------------------------------------------------- gemm128p
// (R5-proven structure; + XCD remap; + y-batch strides for prep GEMMs)
__global__ __launch_bounds__(256) void gemm128p(
    const u16* __restrict__ A1, const u16* __restrict__ A2, int lda, int ksplit,
    const u16* __restrict__ Bt, int ldb,
    const float* __restrict__ b0, const float* __restrict__ b1,
    const float* __restrict__ b2,
    u16* __restrict__ C, int ldc, int K, int relu, int nb,
    long long syA, long long syB, long long syC) {
  __shared__ u16 sm[3][8192];   // per buffer: A[128][32] @0, B[128][32] @4096
  int zy = blockIdx.y;
  A1 += (size_t)zy * syA;
  A2 += (size_t)zy * syA;
  Bt += (size_t)zy * syB;
  C  += (size_t)zy * syC;
  int g = blockIdx.x;
  if ((gridDim.x & 7) == 0) g = (g & 7) * (gridDim.x >> 3) + (g >> 3);
  int m0 = (g / nb) * 128, n0 = (g % nb) * 128;
  int tid = threadIdx.x, lane = tid & 63, w = tid >> 6;
  int wr = w >> 1, wc = w & 1;
  int srow = w * 16 + (lane >> 2);
  int scol = (((lane & 3) ^ ((lane >> 3) & 3)) * 8);
  int m_in = lane & 15;
  int sgrp = lane >> 4;
  int offA[4], offB[4];
#pragma unroll
  for (int mf = 0; mf < 4; mf++) {
    int row = wr * 64 + mf * 16 + m_in;
    offA[mf] = row * 32 + ((sgrp ^ ((row >> 1) & 3)) * 8);
  }
#pragma unroll
  for (int nf = 0; nf < 4; nf++) {
    int row = wc * 64 + nf * 16 + m_in;
    offB[nf] = 4096 + row * 32 + ((sgrp ^ ((row >> 1) & 3)) * 8);
  }
  f32x4 acc[4][4];
#pragma unroll
  for (int i = 0; i < 4; i++)
#pragma unroll
    for (int j = 0; j < 4; j++) acc[i][j] = (f32x4){0.f, 0.f, 0.f, 0.f};

  int nt = K >> 5;
  auto STAGE = [&](int b, int t) {
    int k0 = t * 32;
    const u16* Ab; int kk;
    if (k0 < ksplit) { Ab = A1; kk = k0; } else { Ab = A2; kk = k0 - ksplit; }
    u16* base = &sm[b][0];
    gload16(&Ab[(size_t)(m0 + srow) * lda + kk + scol],      base + w * 512);
    gload16(&Ab[(size_t)(m0 + 64 + srow) * lda + kk + scol], base + 2048 + w * 512);
    gload16(&Bt[(size_t)(n0 + srow) * ldb + k0 + scol],      base + 4096 + w * 512);
    gload16(&Bt[(size_t)(n0 + 64 + srow) * ldb + k0 + scol], base + 6144 + w * 512);
  };

  STAGE(0, 0);
  STAGE(1, 1 < nt ? 1 : nt - 1);
  int cb = 0;
  for (int t = 0; t < nt; ++t) {
    int pf = t + 2 < nt ? t + 2 : nt - 1;
    int pb = cb + 2 >= 3 ? cb - 1 : cb + 2;
    STAGE(pb, pf);
    asm volatile("s_waitcnt vmcnt(8)" ::: "memory");
    asm volatile("s_barrier" ::: "memory");
    const u16* lb = &sm[cb][0];
    s16x8 a_[4], b_[4];
#pragma unroll
    for (int mf = 0; mf < 4; mf++) a_[mf] = *(const s16x8*)&lb[offA[mf]];
#pragma unroll
    for (int nf = 0; nf < 4; nf++) b_[nf] = *(const s16x8*)&lb[offB[nf]];
    __builtin_amdgcn_s_setprio(1);
#pragma unroll
    for (int mf = 0; mf < 4; mf++)
#pragma unroll
      for (int nf = 0; nf < 4; nf++)
        acc[mf][nf] = __builtin_amdgcn_mfma_f32_16x16x32_bf16(
            a_[mf], b_[nf], acc[mf][nf], 0, 0, 0);
    __builtin_amdgcn_s_setprio(0);
    asm volatile("s_barrier" ::: "memory");
    cb = cb + 1 >= 3 ? 0 : cb + 1;
  }
  int r0 = m0 + wr * 64 + (sgrp << 2);
  int cl = lane & 15;
#pragma unroll
  for (int mf = 0; mf < 4; mf++) {
#pragma unroll
    for (int nf = 0; nf < 4; nf++) {
      int col = n0 + wc * 64 + nf * 16 + cl;
      const float* bp = (col < 512) ? b0 : (col < 1024 ? b1 : b2);
      float bv = bp ? bp[col & 511] : 0.f;
#pragma unroll
      for (int r = 0; r < 4; r++) {
        float v = acc[mf][nf][r] + bv;
        if (relu) v = fmaxf(v, 0.f);
        C[(size_t)(r0 + mf * 16 + r) * ldc + col] = f2bf(v);
      }
    }
  }
}

// ---------------------------------------------------------------- gram + mc
// Per seq n: G[t][s] = sum_e Q[t,e]*K[s,e] (Q stride ldq, K stride ldk);
// MC[n,tau] = sum_t G[t][(t-tau)&63] / 512.
__global__ __launch_bounds__(256) void gram_mc_kernel(
    const u16* __restrict__ Q, int ldq, const u16* __restrict__ K, int ldk,
    float* __restrict__ MC) {
  __shared__ u16 lA[64][40];
  __shared__ u16 lB[64][40];
  __shared__ float red[64];
  int n = blockIdx.x;
  int tid = threadIdx.x, lane = tid & 63, w = tid >> 6;
  int sr = tid >> 2, scol = (tid & 3) * 8;
  if (tid < 64) red[tid] = 0.f;
  f32x4 acc[4];
#pragma unroll
  for (int i = 0; i < 4; i++) acc[i] = (f32x4){0.f, 0.f, 0.f, 0.f};
  size_t bq = (size_t)n * 64 * ldq;
  size_t bk = (size_t)n * 64 * ldk;
  for (int k0 = 0; k0 < 512; k0 += 32) {
    *(u16x8*)&lA[sr][scol] = *(const u16x8*)&Q[bq + (size_t)sr * ldq + k0 + scol];
    *(u16x8*)&lB[sr][scol] = *(const u16x8*)&K[bk + (size_t)sr * ldk + k0 + scol];
    __syncthreads();
    int ar = w * 16 + (lane & 15);
    int kk = (lane >> 4) * 8;
    s16x8 af = *(const s16x8*)&lA[ar][kk];
#pragma unroll
    for (int nb = 0; nb < 4; nb++) {
      s16x8 bfr = *(const s16x8*)&lB[nb * 16 + (lane & 15)][kk];
      acc[nb] = __builtin_amdgcn_mfma_f32_16x16x32_bf16(af, bfr, acc[nb], 0, 0, 0);
    }
    __syncthreads();
  }
  int row0 = w * 16 + ((lane >> 4) << 2);
  int cl = lane & 15;
#pragma unroll
  for (int nb = 0; nb < 4; nb++) {
    int col = nb * 16 + cl;
#pragma unroll
    for (int r = 0; r < 4; r++)
      atomicAdd(&red[(row0 + r - col) & 63], acc[nb][r]);
  }
  __syncthreads();
  if (tid < 64) MC[n * 64 + tid] = red[tid] * (1.f / 512.f);
}

// ---------------------------------------------------------------- inst norm
__global__ __launch_bounds__(256) void instnorm_kernel(
    const float* __restrict__ xe, float* __restrict__ MEANS, float* __restrict__ STDEV) {
  int n = blockIdx.x;           // b*21+c
  int b = n / 21, c = n % 21;
  int tid = threadIdx.x;
  float v0 = xe[((size_t)b * 512 + tid) * 21 + c];
  float v1 = xe[((size_t)b * 512 + tid + 256) * 21 + c];
  float s = v0 + v1, ss = v0 * v0 + v1 * v1;
  for (int o = 32; o; o >>= 1) { s += __shfl_down(s, o); ss += __shfl_down(ss, o); }
  __shared__ float rs[4], rss[4];
  if ((tid & 63) == 0) { rs[tid >> 6] = s; rss[tid >> 6] = ss; }
  __syncthreads();
  if (tid == 0) {
    s = rs[0] + rs[1] + rs[2] + rs[3];
    ss = rss[0] + rss[1] + rss[2] + rss[3];
    float mean = s * (1.f / 512.f);
    float var = ss * (1.f / 512.f) - mean * mean;
    MEANS[n] = mean;
    STDEV[n] = sqrtf(var + 1e-5f);
  }
}

// ---------------------------------------------------------------- pos emb
__global__ __launch_bounds__(256) void pe_kernel(float* __restrict__ PE) {
  int i = blockIdx.x * 256 + threadIdx.x;  // 32768
  int p = i >> 9, d = i & 511;
  int k = d >> 1;
  float freq = expf(-(float)(2 * k) * (9.210340371976184f / 512.f));
  float ang = (float)p * freq;
  PE[i] = (d & 1) ? cosf(ang) : sinf(ang);
}

// ---------------------------------------------------------------- patch embed
__global__ __launch_bounds__(256) void patch_kernel(
    const float* __restrict__ xe, const float* __restrict__ wv,
    const float* __restrict__ PE, const float* __restrict__ MEANS,
    const float* __restrict__ STDEV, u16* __restrict__ X) {
  __shared__ float pw[16][512];
  __shared__ float pat[8][16];
  int bx = blockIdx.x;
  int n = bx >> 3, pb = bx & 7;
  int b = n / 21, c = n % 21;
  int tid = threadIdx.x;
  float mean = MEANS[n], inv = 1.f / STDEV[n];
  for (int i = tid; i < 8192; i += 256) pw[i >> 9][i & 511] = wv[i];
  if (tid < 128) {
    int pp = tid >> 4, j = tid & 15;
    int l = (pb * 8 + pp) * 8 + j;
    if (l > 511) l = 511;                       // replication pad
    pat[pp][j] = (xe[((size_t)b * 512 + l) * 21 + c] - mean) * inv;
  }
  __syncthreads();
  for (int i = tid; i < 4096; i += 256) {
    int pp = i >> 9, d = i & 511;
    int p = pb * 8 + pp;
    float s = PE[p * 512 + d];
#pragma unroll
    for (int j = 0; j < 16; j++) s += pat[pp][j] * pw[j][d];
    X[((size_t)n * 64 + p) * 512 + d] = f2bf(s);
  }
}

// ---------------------------------------------------------------- topk + softw
__global__ __launch_bounds__(256) void topk_softw_kernel(
    const float* __restrict__ MC, int* __restrict__ TIDX, float* __restrict__ WSM) {
  __shared__ float g[256];
  __shared__ float gt[64];
  __shared__ int dly[4];
  int tid = threadIdx.x;
  int tau = tid & 63, part = tid >> 6;    // 4-way split over n
  float s = 0.f;
  for (int n = part * 168; n < (part + 1) * 168; n++) s += MC[n * 64 + tau];
  g[tid] = s;
  __syncthreads();
  if (tid < 64) gt[tid] = g[tid] + g[64 + tid] + g[128 + tid] + g[192 + tid];
  __syncthreads();
  if (tid == 0) {
    for (int j = 0; j < 4; j++) {
      int best = 0; float bv = -1e30f;
      for (int t = 0; t < 64; t++) if (gt[t] > bv) { bv = gt[t]; best = t; }
      dly[j] = best;
      TIDX[j] = best;
      gt[best] = -1e30f;
    }
  }
  __syncthreads();
  for (int n = tid; n < 672; n += 256) {
    float v[4], mx = -1e30f;
#pragma unroll
    for (int j = 0; j < 4; j++) { v[j] = MC[n * 64 + dly[j]]; mx = fmaxf(mx, v[j]); }
    float ssum = 0.f;
#pragma unroll
    for (int j = 0; j < 4; j++) { v[j] = __expf(v[j] - mx); ssum += v[j]; }
    float inv = 1.f / ssum;
#pragma unroll
    for (int j = 0; j < 4; j++) WSM[n * 4 + j] = v[j] * inv;
  }
}

// aggX[n,l,:] = sum_j w[n,j] * V[n,(l+delay_j)&63,:]  (V stride ldv, OUT ldo)
// Per-block sequence slab staged in LDS (64 KB): gather hits LDS, not HBM.
__global__ __launch_bounds__(256) void agg_kernel(
    const u16* __restrict__ V, int ldv, const float* __restrict__ WSM,
    const int* __restrict__ TIDX, u16* __restrict__ OUT, int ldo) {
  __shared__ u16 xs[64][512];   // 64 KB
  __shared__ float w[4];
  __shared__ int dly[4];
  int n = blockIdx.x;
  int tid = threadIdx.x;
  if (tid < 4) { w[tid] = WSM[n * 4 + tid]; dly[tid] = TIDX[tid]; }
  // stage the sequence's 64x512 slab (coalesced 16B loads)
  for (int i = tid; i < 64 * 64; i += 256) {
    int l = i >> 6, seg = (i & 63) * 8;
    *(u16x8*)&xs[l][seg] = *(const u16x8*)&V[((size_t)n * 64 + l) * ldv + seg];
  }
  __syncthreads();
  for (int i = tid; i < 64 * 512; i += 256) {
    int l = i >> 9, d = i & 511;
    float s = 0.f;
#pragma unroll
    for (int j = 0; j < 4; j++)
      s += w[j] * bf2f(xs[(l + dly[j]) & 63][d]);
    OUT[((size_t)n * 64 + l) * ldo + d] = f2bf(s);
  }
}

// ---------------------------------------------------------------- MFMA attention
__global__ __launch_bounds__(256) void attn_mfma(u16* __restrict__ QKV) {
  __shared__ u16 lq[64][72], lk[64][72], lvt[64][72], lp[64][72];
  int n = blockIdx.x >> 3, h = blockIdx.x & 7;
  size_t base = (size_t)n * 64 * 1536;
  int qo = h * 64, ko = 512 + h * 64, vo = 1024 + h * 64;
  int tid = threadIdx.x, lane = tid & 63, w = tid >> 6;
  int r = tid >> 2, c0 = (tid & 3) * 16;
  *(u16x8*)&lq[r][c0]     = *(const u16x8*)&QKV[base + (size_t)r * 1536 + qo + c0];
  *(u16x8*)&lq[r][c0 + 8] = *(const u16x8*)&QKV[base + (size_t)r * 1536 + qo + c0 + 8];
  *(u16x8*)&lk[r][c0]     = *(const u16x8*)&QKV[base + (size_t)r * 1536 + ko + c0];
  *(u16x8*)&lk[r][c0 + 8] = *(const u16x8*)&QKV[base + (size_t)r * 1536 + ko + c0 + 8];
  u16x8 v0 = *(const u16x8*)&QKV[base + (size_t)r * 1536 + vo + c0];
  u16x8 v1 = *(const u16x8*)&QKV[base + (size_t)r * 1536 + vo + c0 + 8];
#pragma unroll
  for (int j = 0; j < 8; j++) { lvt[c0 + j][r] = v0[j]; lvt[c0 + 8 + j][r] = v1[j]; }
  __syncthreads();
  int m_in = lane & 15, ks = (lane >> 4) * 8;
  int rq = lane >> 4;
  s16x8 aq0 = *(const s16x8*)&lq[w * 16 + m_in][ks];
  s16x8 aq1 = *(const s16x8*)&lq[w * 16 + m_in][32 + ks];
  f32x4 s4[4];
#pragma unroll
  for (int nf = 0; nf < 4; nf++) {
    s4[nf] = (f32x4){0.f, 0.f, 0.f, 0.f};
    s16x8 b0 = *(const s16x8*)&lk[nf * 16 + m_in][ks];
    s16x8 b1 = *(const s16x8*)&lk[nf * 16 + m_in][32 + ks];
    s4[nf] = __builtin_amdgcn_mfma_f32_16x16x32_bf16(aq0, b0, s4[nf], 0, 0, 0);
    s4[nf] = __builtin_amdgcn_mfma_f32_16x16x32_bf16(aq1, b1, s4[nf], 0, 0, 0);
  }
  float mx[4] = {-1e30f, -1e30f, -1e30f, -1e30f};
#pragma unroll
  for (int nf = 0; nf < 4; nf++)
#pragma unroll
    for (int r4 = 0; r4 < 4; r4++) {
      s4[nf][r4] *= 0.125f;
      mx[r4] = fmaxf(mx[r4], s4[nf][r4]);
    }
#pragma unroll
  for (int o = 1; o < 16; o <<= 1)
#pragma unroll
    for (int r4 = 0; r4 < 4; r4++) mx[r4] = fmaxf(mx[r4], __shfl_xor(mx[r4], o));
  float sum[4] = {0.f, 0.f, 0.f, 0.f};
#pragma unroll
  for (int nf = 0; nf < 4; nf++)
#pragma unroll
    for (int r4 = 0; r4 < 4; r4++) {
      float e = __expf(s4[nf][r4] - mx[r4]);
      s4[nf][r4] = e;
      sum[r4] += e;
    }
#pragma unroll
  for (int o = 1; o < 16; o <<= 1)
#pragma unroll
    for (int r4 = 0; r4 < 4; r4++) sum[r4] += __shfl_xor(sum[r4], o);
#pragma unroll
  for (int nf = 0; nf < 4; nf++)
#pragma unroll
    for (int r4 = 0; r4 < 4; r4++)
      lp[w * 16 + rq * 4 + r4][nf * 16 + m_in] = f2bf(s4[nf][r4] / sum[r4]);
  __syncthreads();
  s16x8 ap0 = *(const s16x8*)&lp[w * 16 + m_in][ks];
  s16x8 ap1 = *(const s16x8*)&lp[w * 16 + m_in][32 + ks];
#pragma unroll
  for (int nf = 0; nf < 4; nf++) {
    f32x4 o4 = (f32x4){0.f, 0.f, 0.f, 0.f};
    s16x8 b0 = *(const s16x8*)&lvt[nf * 16 + m_in][ks];
    s16x8 b1 = *(const s16x8*)&lvt[nf * 16 + m_in][32 + ks];
    o4 = __builtin_amdgcn_mfma_f32_16x16x32_bf16(ap0, b0, o4, 0, 0, 0);
    o4 = __builtin_amdgcn_mfma_f32_16x16x32_bf16(ap1, b1, o4, 0, 0, 0);
#pragma unroll
    for (int r4 = 0; r4 < 4; r4++)
      QKV[base + (size_t)(w * 16 + rq * 4 + r4) * 1536 + qo + nf * 16 + m_in] =
          f2bf(o4[r4]);
  }
}

// ---------------------------------------------------------------- batchnorm
__global__ __launch_bounds__(256) void bn_part(
    const u16* __restrict__ X, float* __restrict__ PS) {
  int ch = blockIdx.x, tid = threadIdx.x;
  float s1a = 0, s2a = 0, s1b = 0, s2b = 0;
  size_t base = (size_t)ch * 128 * 512;
  for (int r = 0; r < 128; r++) {
    float a = bf2f(X[base + (size_t)r * 512 + tid]);
    float b = bf2f(X[base + (size_t)r * 512 + tid + 256]);
    s1a += a; s2a += a * a; s1b += b; s2b += b * b;
  }
  PS[(size_t)(ch * 2 + 0) * 512 + tid] = s1a;
  PS[(size_t)(ch * 2 + 0) * 512 + tid + 256] = s1b;
  PS[(size_t)(ch * 2 + 1) * 512 + tid] = s2a;
  PS[(size_t)(ch * 2 + 1) * 512 + tid + 256] = s2b;
}

__global__ __launch_bounds__(256) void bn_final(
    const float* __restrict__ PS, const float* __restrict__ g,
    const float* __restrict__ b, float* __restrict__ SCALE, float* __restrict__ SHIFT) {
  int d = blockIdx.x * 256 + threadIdx.x;   // < 512
  float s = 0, ss = 0;
  for (int c = 0; c < 336; c++) {
    s += PS[(size_t)(c * 2) * 512 + d];
    ss += PS[(size_t)(c * 2 + 1) * 512 + d];
  }
  float mu = s * (1.f / 43008.f);
  float var = ss * (1.f / 43008.f) - mu * mu;
  float inv = 1.f / sqrtf(var + 1e-5f);
  float sc = g[d] * inv;
  SCALE[d] = sc;
  SHIFT[d] = b[d] - mu * sc;
}

// ---------------------------------------------------------------- bn transpose
__global__ __launch_bounds__(256) void bn_transpose_kernel(
    const u16* __restrict__ X, const float* __restrict__ SCALE,
    const float* __restrict__ SHIFT, u16* __restrict__ ENC) {
  __shared__ u16 t[64][72];
  int n = blockIdx.x >> 3, dc = (blockIdx.x & 7) * 64;
  int tid = threadIdx.x;
  for (int i = tid; i < 4096; i += 256) {
    int p = i >> 6, d = i & 63;
    float v = bf2f(X[((size_t)n * 64 + p) * 512 + dc + d]) * SCALE[dc + d] + SHIFT[dc + d];
    t[p][d] = f2bf(v);
  }
  __syncthreads();
  for (int i = tid; i < 4096; i += 256) {
    int d = i >> 6, p = i & 63;
    ENC[(size_t)n * 32768 + (size_t)(dc + d) * 64 + p] = t[p][d];
  }
}

// ---------------------------------------------------------------- head GEMM
// PART[kc][672][96] partial over 32 K-chunks of 1024
__global__ __launch_bounds__(256) void head_gemm(
    const u16* __restrict__ ENC, const u16* __restrict__ Wht,
    float* __restrict__ PART) {
  __shared__ u16 lA[64][40];
  __shared__ u16 lB[96][40];
  int bm = blockIdx.x;   // 0..10
  int kc = blockIdx.y;   // 0..31
  int tid = threadIdx.x, lane = tid & 63, w = tid >> 6;
  int sr = tid >> 2, sc0 = (tid & 3) * 8;
  f32x4 acc[6];
#pragma unroll
  for (int i = 0; i < 6; i++) acc[i] = (f32x4){0.f, 0.f, 0.f, 0.f};
  for (int kk0 = 0; kk0 < 1024; kk0 += 32) {
    int k0 = kc * 1024 + kk0;
    *(u16x8*)&lA[sr][sc0] =
        *(const u16x8*)&ENC[(size_t)(bm * 64 + sr) * 32768 + k0 + sc0];
    for (int i = tid; i < 96 * 4; i += 256) {
      int rB = i >> 2, seg = (i & 3) * 8;
      *(u16x8*)&lB[rB][seg] = *(const u16x8*)&Wht[(size_t)rB * 32768 + k0 + seg];
    }
    __syncthreads();
    int ar = w * 16 + (lane & 15);
    int kk = (lane >> 4) * 8;
    s16x8 af = *(const s16x8*)&lA[ar][kk];
#pragma unroll
    for (int nb = 0; nb < 6; nb++) {
      s16x8 bfr = *(const s16x8*)&lB[nb * 16 + (lane & 15)][kk];
      acc[nb] = __builtin_amdgcn_mfma_f32_16x16x32_bf16(af, bfr, acc[nb], 0, 0, 0);
    }
    __syncthreads();
  }
  int rb = bm * 64 + w * 16 + ((lane >> 4) << 2);
  int cl = lane & 15;
#pragma unroll
  for (int nb = 0; nb < 6; nb++) {
    int col = nb * 16 + cl;
#pragma unroll
    for (int r = 0; r < 4; r++) {
      int row = rb + r;
      if (row < 672) PART[((size_t)kc * 672 + row) * 96 + col] = acc[nb][r];
    }
  }
}

__global__ __launch_bounds__(256) void head_reduce(
    const float* __restrict__ PART, const float* __restrict__ bh,
    const float* __restrict__ STDEV, const float* __restrict__ MEANS,
    float* __restrict__ OUT) {
  int i = blockIdx.x * 256 + threadIdx.x;
  if (i >= 672 * 96) return;
  int n = i / 96, r = i % 96;
  float s = bh[r];
  for (int kc = 0; kc < 32; kc++) s += PART[((size_t)kc * 672 + n) * 96 + r];
  int b = n / 21, c = n % 21;
  OUT[((size_t)b * 96 + r) * 21 + c] = s * STDEV[n] + MEANS[n];
}

// ============================================================================
extern "C" void kernel_launch(void* const* d_in, const int* in_sizes, int n_in,
                              void* d_out, int out_size, void* d_ws, size_t ws_size,
                              hipStream_t stream) {
  const float* x_enc = (const float*)d_in[0];
  const float* w_val = (const float*)d_in[1];
  const float* Wq_ac = (const float*)d_in[2];
  const float* Wk_ac = (const float*)d_in[3];
  const float* Wv_ac = (const float*)d_in[4];
  const float* Wo_ac = (const float*)d_in[5];
  const float* bq_ac = (const float*)d_in[6];
  const float* bk_ac = (const float*)d_in[7];
  const float* bv_ac = (const float*)d_in[8];
  const float* bo_ac = (const float*)d_in[9];
  const float* Wq_sa = (const float*)d_in[10];
  const float* Wk_sa = (const float*)d_in[11];
  const float* Wv_sa = (const float*)d_in[12];
  const float* Wo_sa = (const float*)d_in[13];
  const float* bq_sa = (const float*)d_in[14];
  const float* bk_sa = (const float*)d_in[15];
  const float* bv_sa = (const float*)d_in[16];
  const float* bo_sa = (const float*)d_in[17];
  const float* WfW   = (const float*)d_in[18];
  const float* bfW   = (const float*)d_in[19];
  const float* W1    = (const float*)d_in[20];
  const float* W2    = (const float*)d_in[21];
  const float* bn_g  = (const float*)d_in[22];
  const float* bn_b  = (const float*)d_in[23];
  const float* W_head = (const float*)d_in[24];
  const float* b_head = (const float*)d_in[25];
  (void)in_sizes; (void)n_in; (void)out_size;
  (void)bq_ac; (void)bk_ac;   // provably cancel in mean_corr top-k/softmax

  // ---- workspace carve-up (~220 MB)
  char* wsp = (char*)d_ws;
  size_t off = 0;
  auto alloc = [&](size_t bytes) -> void* {
    void* p = wsp + off;
    off += (bytes + 255) & ~(size_t)255;
    return p;
  };
  u16* X    = (u16*)alloc((size_t)MROWS * 512 * 2);
  u16* Q3   = (u16*)alloc((size_t)MROWS * 1536 * 2);   // 3 column slices
  u16* SIX   = (u16*)alloc((size_t)3 * 3 * 262144 * 2);  // qsa,ksa,vsa ^T
  u16* W1T   = (u16*)alloc((size_t)3 * 1048576 * 2);
  u16* W2T   = (u16*)alloc((size_t)3 * 1048576 * 2);
  u16* WFT   = (u16*)alloc((size_t)3 * 524288 * 2);
  u16* WORIG = (u16*)alloc((size_t)3 * 5 * 262144 * 2);  // [l][woac|wosa|wvac|wqac|wkac]
  u16* WCOMB = (u16*)alloc((size_t)3 * 524288 * 2);
  u16* WQKT  = (u16*)alloc((size_t)3 * 262144 * 2);      // (Wq·Wk^T)^T per layer
  u16* WHT   = (u16*)alloc((size_t)3145728 * 2);
  u16* TMP   = (u16*)alloc((size_t)3 * 262144 * 2);
  float* PE = (float*)alloc((size_t)32768 * 4);
  float* MEANS = (float*)alloc(672 * 4);
  float* STDEV = (float*)alloc(672 * 4);
  float* MC = (float*)alloc(672 * 64 * 4);
  int* TIDX = (int*)alloc(4 * 4);
  float* WSM = (float*)alloc(672 * 4 * 4);
  float* BNP = (float*)alloc((size_t)336 * 1024 * 4);
  float* SCALE = (float*)alloc(512 * 4);
  float* SHIFT = (float*)alloc(512 * 4);
  float* BOAE = (float*)alloc(3 * 512 * 4);
  float* BCOMB = (float*)alloc(3 * 512 * 4);
  u16* C0 = Q3;          // cols    0..511
  u16* C1 = Q3 + 512;    // cols  512..1023
  u16* C2 = Q3 + 1024;   // cols 1024..1535
  u16* HBUF = Q3;                                  // [21504][2048] = 88 MB
  u16* ENC  = Q3;                                  // head: [672][32768]
  float* HEADP = (float*)X;                        // head partials overlay X (8.3 MB)

  if (off > ws_size) {
    zero_out_kernel<<<252, 256, 0, stream>>>((float*)d_out, 672 * 96);
    return;
  }

  // ---- weight prep
  transpose_cvt_sa<<<dim3(16, 16, 9), dim3(32, 8), 0, stream>>>(
      Wq_sa, Wk_sa, Wv_sa, SIX);
  transpose_cvt_b<<<dim3(16, 64, 3), dim3(32, 8), 0, stream>>>(
      W1, W1T, 512, 2048, 1048576, 1048576);
  transpose_cvt_b<<<dim3(64, 16, 3), dim3(32, 8), 0, stream>>>(
      W2, W2T, 2048, 512, 1048576, 1048576);
  transpose_cvt_b<<<dim3(32, 16, 3), dim3(32, 8), 0, stream>>>(
      WfW, WFT, 1024, 512, 524288, 524288);
  transpose_cvt_b<<<dim3(1024, 3, 1), dim3(32, 8), 0, stream>>>(
      W_head, WHT, 32768, 96, 0, 0);
  cvt_bf16_fifteen<<<dim3(1024, 1, 15), 256, 0, stream>>>(
      Wo_ac, Wo_sa, Wv_ac, Wq_ac, Wk_ac, WORIG);
  boa_eff_kernel<<<3, 512, 0, stream>>>(Wo_ac, bo_ac, bv_ac, BOAE);
  bias_combine<<<3, 512, 0, stream>>>(WfW, bfW, BOAE, bo_sa, BCOMB);
  // prep GEMMs, y-batched over layers (4 launches):
  gemm128p<<<dim3(16, 3), 256, 0, stream>>>(
      WFT, WFT, 1024, 512, WORIG, 512, nullptr, nullptr, nullptr,
      TMP, 512, 512, 0, 4, 524288, 5 * 262144, 262144);
  gemm128p<<<dim3(16, 3), 256, 0, stream>>>(
      TMP, TMP, 512, 512, WORIG + 2 * 262144, 512, nullptr, nullptr, nullptr,
      WCOMB, 1024, 512, 0, 4, 262144, 5 * 262144, 524288);
  gemm128p<<<dim3(16, 3), 256, 0, stream>>>(
      WFT + 512, WFT + 512, 1024, 512, WORIG + 262144, 512,
      nullptr, nullptr, nullptr, WCOMB + 512, 1024, 512, 0, 4,
      524288, 5 * 262144, 524288);
  gemm128p<<<dim3(16, 3), 256, 0, stream>>>(
      WORIG + 4 * 262144, WORIG + 4 * 262144, 512, 512,
      WORIG + 3 * 262144, 512, nullptr, nullptr, nullptr,
      WQKT, 512, 512, 0, 4, 5 * 262144, 5 * 262144, 262144);

  // ---- front end
  instnorm_kernel<<<672, 256, 0, stream>>>(x_enc, MEANS, STDEV);
  pe_kernel<<<128, 256, 0, stream>>>(PE);
  patch_kernel<<<672 * 8, 256, 0, stream>>>(x_enc, w_val, PE, MEANS, STDEV, X);

  // big gemm helper (128x256 pipelined, 2 blk/CU); dmode=1 -> fused decomp
  auto gbig = [&](const u16* A1, const u16* A2, int lda, int ksplit,
                  const u16* Bt, int ldb, const float* b0, const float* b1,
                  const float* b2, u16* C, int ldc, int M, int N, int K,
                  int relu, int dmode) {
    int nb = N / 256;
    if (nb < 1) nb = 1;
    gemm128x256<<<(M / 128) * nb, 512, 0, stream>>>(
        A1, A2, lda, ksplit, Bt, ldb, b0, b1, b2, C, ldc, K, relu, nb, dmode);
  };

  // ---- encoder layers
  for (int l = 0; l < 3; l++) {
    const u16* qkv_sa = SIX + (size_t)l * 3 * 262144;        // [1536][512]
    const u16* wqkt   = WQKT + (size_t)l * 262144;
    const u16* w1     = W1T + (size_t)l * 1048576;
    const u16* w2     = W2T + (size_t)l * 1048576;
    const u16* wcomb  = WCOMB + (size_t)l * 524288;
    // SA: fused QKV (N=1536) -> Q3 [q|k|v]
    gbig(X, X, 512, 512, qkv_sa, 512, bq_sa + l * 512, bk_sa + l * 512,
         bv_sa + l * 512, Q3, 1536, MROWS, 1536, 512, 0, 0);
    attn_mfma<<<5376, 256, 0, stream>>>(Q3);                    // attnout -> C0
    // AC: Y = X @ (Wq·Wk^T)  (N=512, biases provably cancel) -> C1
    gbig(X, X, 512, 512, wqkt, 512, nullptr, nullptr, nullptr,
         C1, 1536, MROWS, 512, 512, 0, 0);
    gram_mc_kernel<<<672, 256, 0, stream>>>(C1, 1536, X, 512, MC);
    topk_softw_kernel<<<1, 256, 0, stream>>>(MC, TIDX, WSM);
    // aggX from X directly (Wv fold), LDS-staged gather -> C2
    agg_kernel<<<672, 256, 0, stream>>>(X, 512, WSM, TIDX, C2, 1536);
    // fused+decomp: X <- decomp(X + aggX@WcombA + attnout@WcombS + bcomb)
    gbig(C2, C0, 1536, 512, wcomb, 1024, BCOMB + l * 512, nullptr, nullptr,
         X, 512, MROWS, 512, 1024, 0, 1);
    // FFN in 2 M-chunks of 21504; W2 fused with decomp (writes X in place)
    for (int c = 0; c < 2; c++) {
      const u16* Xc = X + (size_t)c * 21504 * 512;
      u16* Xcw = X + (size_t)c * 21504 * 512;
      gbig(Xc, Xc, 512, 512, w1, 512, nullptr, nullptr, nullptr,
           HBUF, 2048, 21504, 2048, 512, 1, 0);
      gbig(HBUF, HBUF, 2048, 2048, w2, 2048, nullptr, nullptr, nullptr,
           Xcw, 512, 21504, 512, 2048, 0, 1);
    }
  }

  // ---- batchnorm + head
  bn_part<<<336, 256, 0, stream>>>(X, BNP);
  bn_final<<<2, 256, 0, stream>>>(BNP, bn_g, bn_b, SCALE, SHIFT);
  bn_transpose_kernel<<<672 * 8, 256, 0, stream>>>(X, SCALE, SHIFT, ENC);
  head_gemm<<<dim3(11, 32), 256, 0, stream>>>(ENC, WHT, HEADP);
  head_reduce<<<252, 256, 0, stream>>>(HEADP, b_head, STDEV, MEANS, (float*)d_out);
}